// Round 22
// baseline (446.786 us; speedup 1.0000x reference)
//
#include <hip/hip_runtime.h>
#include <hip/hip_bf16.h>
#include <cstdint>
#include <cstddef>

typedef unsigned short u16;
typedef unsigned int u32;
using f32x4 = __attribute__((ext_vector_type(4))) float;
using s16x8 = __attribute__((ext_vector_type(8))) short;

#define NB   16
#define NH   56
#define NW   56
#define NDIM 384
#define NMED 768
#define NFIL 4
#define NRH  96
#define NWF  29
#define NPIX (NB*NH*NW)   // 50176

__device__ __forceinline__ float bf2f(u16 u){
  union { float f; u32 i; } w; w.i = ((u32)u) << 16; return w.f;
}
__device__ __forceinline__ u16 f2bf(float f){
  union { float f; u32 i; } w; w.f = f;
  u32 i = w.i;
  return (u16)((i + 0x7fffu + ((i >> 16) & 1u)) >> 16);
}
__device__ __forceinline__ u32 packbf(float r, float i){
  return (u32)f2bf(r) | ((u32)f2bf(i) << 16);
}
// swizzled LDS index for [row][col64] bf16 tiles (breaks 128B-stride bank conflicts)
__device__ __forceinline__ int lix(int row, int col){
  return (row*64 + col) ^ ((row & 7) << 3);
}

#define GLD16(gp, lp) __builtin_amdgcn_global_load_lds( \
    (const __attribute__((address_space(1))) void*)(gp), \
    (__attribute__((address_space(3))) void*)(lp), 16, 0, 0)

// ---------------- precompute bf16 twiddle matrix images (pre-swizzled LDS layout) ----
__global__ __launch_bounds__(256) void k_prep(u16* gE, u16* gC, u16* gS, u16* gAB){
  int mat = blockIdx.x;
  int t = threadIdx.x;
  int row = t >> 2, cb = (t & 3)*16;
  const float PI2 = 6.28318530717958647692f;
  u16* dst = (mat==0) ? gE : (mat==1) ? gC : (mat==2) ? gS : gAB;
  #pragma unroll
  for (int q = 0; q < 4; ++q){
    ushort4 v4;
    #pragma unroll
    for (int m = 0; m < 4; ++m){
      int col = cb + q*4 + m;
      float val = 0.f;
      if (mat == 0){
        int k2 = row >> 1, w = col;
        if (k2 < NWF && w < 56){
          float a = PI2 * (float)((k2*w) % 56) * (1.0f/56.0f);
          val = (row & 1) ? -sinf(a) : cosf(a);
        }
      } else if (mat <= 2){
        if (row < 56 && col < 56){
          float a = PI2 * (float)((row*col) % 56) * (1.0f/56.0f);
          val = (mat == 1) ? cosf(a) : sinf(a);
        }
      } else {
        int w = row, k2 = col >> 1;
        if (w < 56 && k2 < NWF){
          float al, be;
          if (k2 == 0)       { al = 1.0f; be = 0.0f; }
          else if (k2 == 28) { al = (w & 1) ? -1.0f : 1.0f; be = 0.0f; }
          else {
            float a = PI2 * (float)((k2*w) % 56) * (1.0f/56.0f);
            al = 2.0f*cosf(a); be = -2.0f*sinf(a);
          }
          val = (col & 1) ? be : al;
        }
      }
      ((u16*)&v4)[m] = f2bf(val);
    }
    *(ushort4*)&dst[lix(row, cb + q*4)] = v4;
  }
}

__global__ __launch_bounds__(256) void k_wt(const float* __restrict__ w, u16* __restrict__ wt, int K, int N){
  int i = blockIdx.x*256 + threadIdx.x;
  if (i >= K*N) return;
  int k = i / N, n = i % N;
  wt[(size_t)n*K + k] = f2bf(w[i]);
}

// ---------------- routing (gpart also emits bf16 copy of x) ----------------

__global__ __launch_bounds__(384) void k_gpart(const float* __restrict__ x, float* __restrict__ gp,
    u16* __restrict__ xbf){
  int d = threadIdx.x, h = blockIdx.x, b = blockIdx.y;
  size_t base = ((size_t)(b*NH + h)*NW)*NDIM + d;
  const float* xp = x + base;
  u16* xo = xbf + base;
  float s = 0.f;
  for (int w = 0; w < NW; ++w){
    float f = xp[(size_t)w*NDIM];
    s += f;
    xo[(size_t)w*NDIM] = f2bf(f);
  }
  gp[(size_t)(b*NH + h)*NDIM + d] = s;
}

__global__ __launch_bounds__(384) void k_gfinal(const float* __restrict__ gp, float* __restrict__ g){
  int d = threadIdx.x, b = blockIdx.x;
  float s = 0.f;
  for (int h = 0; h < NH; ++h) s += gp[(size_t)(b*NH + h)*NDIM + d];
  g[b*NDIM + d] = s * (1.0f/3136.0f);
}

__global__ __launch_bounds__(128) void k_rmlp1(const float* __restrict__ g,
    const float* __restrict__ w_r1, const float* __restrict__ rs, const float* __restrict__ rb,
    float* __restrict__ hbuf){
  int b = blockIdx.x, t = threadIdx.x;
  __shared__ float lg[NDIM];
  for (int i = t; i < NDIM; i += 128) lg[i] = g[b*NDIM + i];
  __syncthreads();
  if (t < NRH){
    float a = 0.f;
    #pragma unroll 8
    for (int d = 0; d < NDIM; ++d) a = fmaf(lg[d], w_r1[d*NRH + t], a);
    float r = fmaxf(a, 0.f);
    hbuf[b*NRH + t] = rs[0]*r*r + rb[0];
  }
}

__global__ __launch_bounds__(256) void k_rmlp2(const float* __restrict__ hbuf,
    const float* __restrict__ w_r2, float* __restrict__ rout){
  int b = blockIdx.y;
  int c = blockIdx.x*256 + threadIdx.x;
  __shared__ float lh[NRH];
  if (threadIdx.x < NRH) lh[threadIdx.x] = hbuf[b*NRH + threadIdx.x];
  __syncthreads();
  float a0 = 0.f, a1 = 0.f, a2 = 0.f, a3 = 0.f;
  #pragma unroll 4
  for (int i = 0; i < NRH; ++i){
    float hv = lh[i];
    const float* wp = w_r2 + (size_t)i*(NFIL*NMED) + c;
    a0 = fmaf(hv, wp[0*NMED], a0);
    a1 = fmaf(hv, wp[1*NMED], a1);
    a2 = fmaf(hv, wp[2*NMED], a2);
    a3 = fmaf(hv, wp[3*NMED], a3);
  }
  float m = fmaxf(fmaxf(a0, a1), fmaxf(a2, a3));
  float e0 = expf(a0-m), e1 = expf(a1-m), e2 = expf(a2-m), e3 = expf(a3-m);
  float inv = 1.0f/(e0+e1+e2+e3);
  rout[(b*NFIL+0)*NMED + c] = e0*inv;
  rout[(b*NFIL+1)*NMED + c] = e1*inv;
  rout[(b*NFIL+2)*NMED + c] = e2*inv;
  rout[(b*NFIL+3)*NMED + c] = e3*inv;
}

// ---------------- bf16 MFMA GEMM (global_load_lds staged; bf16 A) ----------
// T2 both-sides swizzle: LDS dest linear; global source 16B-chunk XOR (row&3);
// fragment reads apply the same XOR.
template<int EPI>
__global__ __launch_bounds__(256) void gemm_glds(const u16* __restrict__ A, const u16* __restrict__ BT,
    float* __restrict__ Cf, u16* __restrict__ Cb, int M, int N, int K,
    const float* __restrict__ scp, const float* __restrict__ bip){
  __shared__ __align__(16) u16 lA[128*32];
  __shared__ __align__(16) u16 lB[128*32];
  int t = threadIdx.x;

  int bid = blockIdx.y * gridDim.x + blockIdx.x;
  int nwg = gridDim.x * gridDim.y;
  int q8 = nwg >> 3, r8 = nwg & 7;
  int xcd = bid & 7, idx = bid >> 3;
  int swz = (xcd < r8 ? xcd*(q8+1) : r8*(q8+1) + (xcd-r8)*q8) + idx;
  int m0 = (swz / gridDim.x) * 128;
  int n0 = (swz % gridDim.x) * 128;

  int lane = t & 63, wid = t >> 6;
  int wr = (wid >> 1) * 64, wc = (wid & 1) * 64;
  int lr = lane & 15, kg = lane >> 4;
  f32x4 acc[4][4] = {};

  int srow0 = (lane >> 2);
  int scj   = (lane & 3);

  for (int k0 = 0; k0 < K; k0 += 32){
    #pragma unroll
    for (int j = 0; j < 2; ++j){
      int row = (wid*2 + j)*16 + srow0;
      int gcj = scj ^ (row & 3);
      GLD16(&A [(size_t)(m0+row)*K + k0 + gcj*8], &lA[row*32 + scj*8]);
      GLD16(&BT[(size_t)(n0+row)*K + k0 + gcj*8], &lB[row*32 + scj*8]);
    }
    __syncthreads();
    s16x8 af[4], bf[4];
    #pragma unroll
    for (int fm = 0; fm < 4; ++fm){
      int r = wr + fm*16 + lr;
      af[fm] = *(const s16x8*)(&lA[r*32 + (kg ^ (r & 3))*8]);
    }
    #pragma unroll
    for (int fn = 0; fn < 4; ++fn){
      int r = wc + fn*16 + lr;
      bf[fn] = *(const s16x8*)(&lB[r*32 + (kg ^ (r & 3))*8]);
    }
    #pragma unroll
    for (int fm = 0; fm < 4; ++fm)
      #pragma unroll
      for (int fn = 0; fn < 4; ++fn)
        acc[fm][fn] = __builtin_amdgcn_mfma_f32_16x16x32_bf16(af[fm], bf[fn], acc[fm][fn], 0, 0, 0);
    __syncthreads();
  }

  float sc = 0.f, bi = 0.f;
  if (EPI == 0){ sc = scp[0]; bi = bip[0]; }
  #pragma unroll
  for (int fm = 0; fm < 4; ++fm)
    #pragma unroll
    for (int fn = 0; fn < 4; ++fn)
      #pragma unroll
      for (int r = 0; r < 4; ++r){
        int gm = m0 + wr + fm*16 + kg*4 + r;
        int gn = n0 + wc + fn*16 + lr;
        float val = acc[fm][fn][r];
        if (EPI == 0){
          float rl = fmaxf(val, 0.f);
          val = fmaf(sc*rl, rl, bi);
          Cb[(size_t)gm*N + gn] = f2bf(val);
        } else {
          Cf[(size_t)gm*N + gn] = val;
        }
      }
}

// ---------------- depthwise 3x3 conv + BN partials ----------------
// v3: XCD-contiguous block swizzle + x-unroll-by-2 with 2-column prefetch.
// grid (2, NH, NB) x 192 thr; psum/psq indexed [(b*NH+y)*2+seg].

__global__ __launch_bounds__(192) void k_dwconv(const u16* __restrict__ v, const float* __restrict__ kw,
    const float* __restrict__ kb, u16* __restrict__ locraw,
    float* __restrict__ psum, float* __restrict__ psq){
  int t = threadIdx.x;
  int id = blockIdx.x + 2*(blockIdx.y + (int)(56*blockIdx.z));
  int swz = (id & 7)*224 + (id >> 3);
  int seg = swz & 1;
  int y   = (swz >> 1) % 56;
  int b   = swz / 112;

  int c = t*4;
  float kk[3][3][4];
  #pragma unroll
  for (int r = 0; r < 3; ++r)
    #pragma unroll
    for (int s = 0; s < 3; ++s)
      #pragma unroll
      for (int q = 0; q < 4; ++q)
        kk[r][s][q] = kw[(r*3+s)*NMED + c + q];
  float bias[4];
  #pragma unroll
  for (int q = 0; q < 4; ++q) bias[q] = kb[c + q];

  bool vr0 = (y > 0), vr2 = (y < NH-1);
  const u16* r0 = v + ((size_t)((b*NH + y-1)*NW))*NMED + c;
  const u16* r1 = v + ((size_t)((b*NH + y  )*NW))*NMED + c;
  const u16* r2 = v + ((size_t)((b*NH + y+1)*NW))*NMED + c;

  auto LD = [&](const u16* rp, bool ok, int x, float o[4]){
    if (ok && (unsigned)x < (unsigned)NW){
      ushort4 u = *(const ushort4*)&rp[(size_t)x*NMED];
      o[0]=bf2f(u.x); o[1]=bf2f(u.y); o[2]=bf2f(u.z); o[3]=bf2f(u.w);
    } else { o[0]=0.f; o[1]=0.f; o[2]=0.f; o[3]=0.f; }
  };
  auto LD3 = [&](int x, float col[3][4]){
    LD(r0, vr0, x, col[0]); LD(r1, true, x, col[1]); LD(r2, vr2, x, col[2]);
  };

  int x0 = seg*28;
  float c0[3][4], c1[3][4], c2[3][4], c3[3][4];
  LD3(x0-1, c0); LD3(x0, c1); LD3(x0+1, c2); LD3(x0+2, c3);

  float sum[4] = {0,0,0,0}, sq[4] = {0,0,0,0};
  u16* op = locraw + ((size_t)(b*NH + y)*NW)*NMED + c;

  for (int x = x0; x < x0+28; x += 2){
    float n0[3][4], n1[3][4];
    LD3(x+3, n0); LD3(x+4, n1);

    float o0[4], o1[4];
    #pragma unroll
    for (int q = 0; q < 4; ++q){
      float t0 = bias[q];
      t0 = fmaf(c0[0][q], kk[0][0][q], t0);
      t0 = fmaf(c1[0][q], kk[0][1][q], t0);
      t0 = fmaf(c2[0][q], kk[0][2][q], t0);
      t0 = fmaf(c0[1][q], kk[1][0][q], t0);
      t0 = fmaf(c1[1][q], kk[1][1][q], t0);
      t0 = fmaf(c2[1][q], kk[1][2][q], t0);
      t0 = fmaf(c0[2][q], kk[2][0][q], t0);
      t0 = fmaf(c1[2][q], kk[2][1][q], t0);
      t0 = fmaf(c2[2][q], kk[2][2][q], t0);
      o0[q] = t0;
      sum[q] += t0; sq[q] = fmaf(t0, t0, sq[q]);
      float t1 = bias[q];
      t1 = fmaf(c1[0][q], kk[0][0][q], t1);
      t1 = fmaf(c2[0][q], kk[0][1][q], t1);
      t1 = fmaf(c3[0][q], kk[0][2][q], t1);
      t1 = fmaf(c1[1][q], kk[1][0][q], t1);
      t1 = fmaf(c2[1][q], kk[1][1][q], t1);
      t1 = fmaf(c3[1][q], kk[1][2][q], t1);
      t1 = fmaf(c1[2][q], kk[2][0][q], t1);
      t1 = fmaf(c2[2][q], kk[2][1][q], t1);
      t1 = fmaf(c3[2][q], kk[2][2][q], t1);
      o1[q] = t1;
      sum[q] += t1; sq[q] = fmaf(t1, t1, sq[q]);
    }
    ushort4 ov0, ov1;
    ov0.x = f2bf(o0[0]); ov0.y = f2bf(o0[1]); ov0.z = f2bf(o0[2]); ov0.w = f2bf(o0[3]);
    ov1.x = f2bf(o1[0]); ov1.y = f2bf(o1[1]); ov1.z = f2bf(o1[2]); ov1.w = f2bf(o1[3]);
    *(ushort4*)&op[(size_t)x*NMED]     = ov0;
    *(ushort4*)&op[(size_t)(x+1)*NMED] = ov1;
    #pragma unroll
    for (int r = 0; r < 3; ++r)
      #pragma unroll
      for (int q = 0; q < 4; ++q){
        c0[r][q] = c2[r][q]; c1[r][q] = c3[r][q];
        c2[r][q] = n0[r][q]; c3[r][q] = n1[r][q];
      }
  }
  size_t pbase = ((size_t)((b*NH + y)*2 + seg))*NMED + c;
  float4 s4; s4.x=sum[0]; s4.y=sum[1]; s4.z=sum[2]; s4.w=sum[3];
  float4 q4; q4.x=sq[0];  q4.y=sq[1];  q4.z=sq[2];  q4.w=sq[3];
  *(float4*)&psum[pbase] = s4;
  *(float4*)&psq[pbase]  = q4;
}

// ---- BN reduction, two-stage parallel ----
__global__ __launch_bounds__(256) void k_bnpart(const float* __restrict__ psum, const float* __restrict__ psq,
    float* __restrict__ ps2, float* __restrict__ pq2){
  int idx = blockIdx.x*256 + threadIdx.x;
  int c  = idx % NMED;
  int jl = idx / NMED;
  float s = 0.f, q = 0.f;
  #pragma unroll
  for (int i = 0; i < (NB*NH*2)/32; ++i){
    int j = jl + i*32;
    s += psum[(size_t)j*NMED + c];
    q += psq [(size_t)j*NMED + c];
  }
  ps2[(size_t)jl*NMED + c] = s;
  pq2[(size_t)jl*NMED + c] = q;
}

__global__ __launch_bounds__(256) void k_bnfinal(const float* __restrict__ ps2, const float* __restrict__ pq2,
    const float* __restrict__ gamma, const float* __restrict__ beta,
    float* __restrict__ bnsc, float* __restrict__ bnsh){
  int c = blockIdx.x*256 + threadIdx.x;
  if (c >= NMED) return;
  float s = 0.f, q = 0.f;
  #pragma unroll 8
  for (int j = 0; j < 32; ++j){ s += ps2[(size_t)j*NMED + c]; q += pq2[(size_t)j*NMED + c]; }
  float mu  = s * (1.0f/(float)NPIX);
  float var = q * (1.0f/(float)NPIX) - mu*mu;
  float sc = gamma[c] * rsqrtf(var + 1e-5f);
  bnsc[c] = sc;
  bnsh[c] = beta[c] - mu*sc;
}

// ---------------- spectral stages (all MFMA) ----------------
// A1p packs (re,im) bf16 into one u32 per element: lo16=re, hi16=im.

// forward rDFT along W, 2 h-rows per block (E fragments reused across rows).
__global__ __launch_bounds__(256) void k_fftw_mfma(const u16* __restrict__ v,
    u32* __restrict__ A1p, const u16* __restrict__ gE){
  __shared__ u16 sE[64*64];        // 8 KB
  __shared__ u16 sV[2][128*64];    // 32 KB
  int t = threadIdx.x;
  int cs = blockIdx.x, hp = blockIdx.y, bz = blockIdx.z;

  ((int4*)sE)[t]       = ((const int4*)gE)[t];
  ((int4*)sE)[t + 256] = ((const int4*)gE)[t + 256];

  #pragma unroll
  for (int rr = 0; rr < 2; ++rr){
    int h = hp*2 + rr;
    int cg = (t & 15) * 8;
    int wq = (t >> 4) * 4;
    u16 buf[4][8];
    #pragma unroll
    for (int dw = 0; dw < 4; ++dw){
      int w = wq + dw;
      if (w < 56){
        *(int4*)&buf[dw][0] = *(const int4*)&v[((size_t)((bz*NH + h)*NW) + w)*NMED + (size_t)cs*128 + cg];
      } else {
        #pragma unroll
        for (int j = 0; j < 8; ++j) buf[dw][j] = 0;
      }
    }
    #pragma unroll
    for (int j = 0; j < 8; ++j){
      u16 tmp[4] = {buf[0][j], buf[1][j], buf[2][j], buf[3][j]};
      *(uint2*)&sV[rr][lix(cg + j, wq)] = *(uint2*)tmp;
    }
  }
  __syncthreads();

  int lane = t & 63, wid = t >> 6;
  int lr = lane & 15, kg = lane >> 4;
  int wn0 = wid * 32;
  f32x4 acc[2][4][2] = {};

  #pragma unroll
  for (int ks = 0; ks < 2; ++ks){
    int k0 = ks*32 + kg*8;
    s16x8 fE[4];
    #pragma unroll
    for (int mi = 0; mi < 4; ++mi) fE[mi] = *(const s16x8*)&sE[lix(mi*16 + lr, k0)];
    #pragma unroll
    for (int rr = 0; rr < 2; ++rr){
      #pragma unroll
      for (int ni = 0; ni < 2; ++ni){
        s16x8 bv = *(const s16x8*)&sV[rr][lix(wn0 + ni*16 + lr, k0)];
        #pragma unroll
        for (int mi = 0; mi < 4; ++mi)
          acc[rr][mi][ni] = __builtin_amdgcn_mfma_f32_16x16x32_bf16(fE[mi], bv, acc[rr][mi][ni], 0, 0, 0);
      }
    }
  }

  #pragma unroll
  for (int rr = 0; rr < 2; ++rr){
    int h = hp*2 + rr;
    size_t gb = ((size_t)bz*NWF*NH)*NMED + (size_t)h*NMED + (size_t)cs*128;
    #pragma unroll
    for (int mi = 0; mi < 4; ++mi){
      #pragma unroll
      for (int rp = 0; rp < 2; ++rp){
        int j0 = mi*16 + kg*4 + rp*2;
        int k2 = j0 >> 1;
        if (k2 < NWF){
          #pragma unroll
          for (int ni = 0; ni < 2; ++ni){
            int c = wn0 + ni*16 + lr;
            A1p[gb + (size_t)k2*NH*NMED + c] = packbf(acc[rr][mi][ni][rp*2], acc[rr][mi][ni][rp*2+1]);
          }
        }
      }
    }
  }
}

// Fused H-stage via MFMA, 64-channel tiles.
// P = E_f X ; P' = P .* W /3136 ; Q = E_i P'. In-place on A1p.
__global__ __launch_bounds__(256) void k_ffth_fused(u32* __restrict__ A1p,
    const u16* __restrict__ gC, const u16* __restrict__ gS,
    const float* __restrict__ rout, const float* __restrict__ cw){
  __shared__ u16 sC[64*64], sS[64*64];
  __shared__ u16 sXr[64*64], sXi[64*64];
  __shared__ float cwS[56*8];
  int t = threadIdx.x;
  int cs = blockIdx.x, k2 = blockIdx.y, bz = blockIdx.z;
  size_t gbase = ((size_t)(bz*NWF + k2)*NH)*NMED + (size_t)cs*64;

  ((int4*)sC)[t]       = ((const int4*)gC)[t];
  ((int4*)sC)[t + 256] = ((const int4*)gC)[t + 256];
  ((int4*)sS)[t]       = ((const int4*)gS)[t];
  ((int4*)sS)[t + 256] = ((const int4*)gS)[t + 256];

  for (int j = t; j < 56*8; j += 256){
    int k1 = j >> 3, f = j & 7;
    cwS[j] = cw[((size_t)(k1*NWF + k2))*8 + f];
  }
  {
    int c = t & 63;
    int hg = t >> 6;
    #pragma unroll
    for (int q = 0; q < 4; ++q){
      int h = hg*16 + q*4;
      u32 u0=0, u1=0, u2=0, u3=0;
      if (h < 56){
        const u32* gp = &A1p[gbase + (size_t)h*NMED + c];
        u0 = gp[0*NMED]; u1 = gp[1*NMED]; u2 = gp[2*NMED]; u3 = gp[3*NMED];
      }
      uint2 rr, ii;
      rr.x = (u0 & 0xffffu) | (u1 << 16);
      rr.y = (u2 & 0xffffu) | (u3 << 16);
      ii.x = (u0 >> 16) | (u1 & 0xffff0000u);
      ii.y = (u2 >> 16) | (u3 & 0xffff0000u);
      *(uint2*)&sXr[lix(c, h)] = rr;
      *(uint2*)&sXi[lix(c, h)] = ii;
    }
  }
  __syncthreads();

  int lane = t & 63, wid = t >> 6;
  int lr = lane & 15, kg = lane >> 4;
  int wn0 = wid * 16;

  f32x4 aR[4], aI[4];
  #pragma unroll
  for (int mi = 0; mi < 4; ++mi){ aR[mi] = (f32x4){0,0,0,0}; aI[mi] = (f32x4){0,0,0,0}; }

  #pragma unroll
  for (int ks = 0; ks < 2; ++ks){
    int k0 = ks*32 + kg*8;
    s16x8 fC[4], fS[4];
    #pragma unroll
    for (int mi = 0; mi < 4; ++mi){
      fC[mi] = *(const s16x8*)&sC[lix(mi*16 + lr, k0)];
      fS[mi] = *(const s16x8*)&sS[lix(mi*16 + lr, k0)];
    }
    s16x8 xr = *(const s16x8*)&sXr[lix(wn0 + lr, k0)];
    s16x8 xi = *(const s16x8*)&sXi[lix(wn0 + lr, k0)];
    uint4 xu = *(uint4*)&xr;
    xu.x ^= 0x80008000u; xu.y ^= 0x80008000u; xu.z ^= 0x80008000u; xu.w ^= 0x80008000u;
    s16x8 xrn = *(s16x8*)&xu;
    #pragma unroll
    for (int mi = 0; mi < 4; ++mi){
      aR[mi] = __builtin_amdgcn_mfma_f32_16x16x32_bf16(fC[mi], xr,  aR[mi], 0,0,0);
      aR[mi] = __builtin_amdgcn_mfma_f32_16x16x32_bf16(fS[mi], xi,  aR[mi], 0,0,0);
      aI[mi] = __builtin_amdgcn_mfma_f32_16x16x32_bf16(fC[mi], xi,  aI[mi], 0,0,0);
      aI[mi] = __builtin_amdgcn_mfma_f32_16x16x32_bf16(fS[mi], xrn, aI[mi], 0,0,0);
    }
  }
  __syncthreads();

  const float inv = 1.0f/3136.0f;
  float rv0, rv1, rv2, rv3;
  {
    int cg = cs*64 + wn0 + lr;
    rv0 = rout[(bz*NFIL+0)*NMED + cg];
    rv1 = rout[(bz*NFIL+1)*NMED + cg];
    rv2 = rout[(bz*NFIL+2)*NMED + cg];
    rv3 = rout[(bz*NFIL+3)*NMED + cg];
  }
  #pragma unroll
  for (int mi = 0; mi < 4; ++mi){
    #pragma unroll
    for (int r = 0; r < 4; ++r){
      int k1 = mi*16 + kg*4 + r;
      float c0=0,c1=0,c2=0,c3=0,c4=0,c5=0,c6=0,c7=0;
      if (k1 < 56){
        const float* cp = cwS + k1*8;
        c0=cp[0]; c1=cp[1]; c2=cp[2]; c3=cp[3]; c4=cp[4]; c5=cp[5]; c6=cp[6]; c7=cp[7];
      }
      float wr = rv0*c0 + rv1*c2 + rv2*c4 + rv3*c6;
      float wi = rv0*c1 + rv1*c3 + rv2*c5 + rv3*c7;
      float pr = aR[mi][r], pi = aI[mi][r];
      float qr = (pr*wr - pi*wi) * inv;
      float qi = (pr*wi + pi*wr) * inv;
      int cl = wn0 + lr;
      sXr[lix(cl, k1)] = f2bf(qr);
      sXi[lix(cl, k1)] = f2bf(qi);
    }
  }
  __syncthreads();

  #pragma unroll
  for (int mi = 0; mi < 4; ++mi){ aR[mi] = (f32x4){0,0,0,0}; aI[mi] = (f32x4){0,0,0,0}; }
  #pragma unroll
  for (int ks = 0; ks < 2; ++ks){
    int k0 = ks*32 + kg*8;
    s16x8 fC[4], fS[4];
    #pragma unroll
    for (int mi = 0; mi < 4; ++mi){
      fC[mi] = *(const s16x8*)&sC[lix(mi*16 + lr, k0)];
      fS[mi] = *(const s16x8*)&sS[lix(mi*16 + lr, k0)];
    }
    s16x8 pr = *(const s16x8*)&sXr[lix(wn0 + lr, k0)];
    s16x8 pi = *(const s16x8*)&sXi[lix(wn0 + lr, k0)];
    uint4 pu = *(uint4*)&pi;
    pu.x ^= 0x80008000u; pu.y ^= 0x80008000u; pu.z ^= 0x80008000u; pu.w ^= 0x80008000u;
    s16x8 pin = *(s16x8*)&pu;
    #pragma unroll
    for (int mi = 0; mi < 4; ++mi){
      aR[mi] = __builtin_amdgcn_mfma_f32_16x16x32_bf16(fC[mi], pr,  aR[mi], 0,0,0);
      aR[mi] = __builtin_amdgcn_mfma_f32_16x16x32_bf16(fS[mi], pin, aR[mi], 0,0,0);
      aI[mi] = __builtin_amdgcn_mfma_f32_16x16x32_bf16(fC[mi], pi,  aI[mi], 0,0,0);
      aI[mi] = __builtin_amdgcn_mfma_f32_16x16x32_bf16(fS[mi], pr,  aI[mi], 0,0,0);
    }
  }

  #pragma unroll
  for (int mi = 0; mi < 4; ++mi){
    #pragma unroll
    for (int r = 0; r < 4; ++r){
      int n1 = mi*16 + kg*4 + r;
      if (n1 < 56){
        int cl = wn0 + lr;
        A1p[gbase + (size_t)n1*NMED + cl] = packbf(aR[mi][r], aI[mi][r]);
      }
    }
  }
}

// inverse along W via MFMA, 64-channel tiles, 4 n1-rows per block (v3).
// Swapped operands: output fragment row=channel (4 consecutive/lane), col=w.
// sA table and fA fragments amortized over 4 rows; 32 staged Q-loads in flight.
__global__ __launch_bounds__(256) void k_ifftw_mfma(const u32* __restrict__ Qp,
    const u16* __restrict__ gAB, const u16* __restrict__ locraw,
    const float* __restrict__ bnsc, const float* __restrict__ bnsh,
    const float* __restrict__ lsp, const float* __restrict__ lbp, u16* __restrict__ sbuf){
  __shared__ u16 sA[64*64];       // 8 KB
  __shared__ u16 sQ[4][64*64];    // 32 KB -> total 40 KB
  int t = threadIdx.x;
  int cs = blockIdx.x, np = blockIdx.y, bz = blockIdx.z;

  ((int4*)sA)[t]       = ((const int4*)gAB)[t];
  ((int4*)sA)[t + 256] = ((const int4*)gAB)[t + 256];

  {
    int c = t & 63;
    int g = t >> 6;
    #pragma unroll
    for (int rr = 0; rr < 4; ++rr){
      int n1 = np*4 + rr;
      size_t qb = (((size_t)bz*NWF)*NH + n1)*NMED + (size_t)cs*64 + c;
      u32 qv[8];
      #pragma unroll
      for (int i = 0; i < 8; ++i){
        int k2 = 4*i + g;
        qv[i] = (k2 < NWF) ? Qp[qb + (size_t)k2*NH*NMED] : 0u;
      }
      #pragma unroll
      for (int i = 0; i < 8; ++i){
        int k2 = 4*i + g;
        *(u32*)&sQ[rr][lix(c, 2*k2)] = qv[i];
      }
    }
  }
  __syncthreads();

  int lane = t & 63, wid = t >> 6;
  int lr = lane & 15, kg = lane >> 4;
  int wn0 = wid * 16;
  f32x4 acc[4][4] = {};

  #pragma unroll
  for (int ks = 0; ks < 2; ++ks){
    int k0 = ks*32 + kg*8;
    s16x8 fA[4];
    #pragma unroll
    for (int mi = 0; mi < 4; ++mi) fA[mi] = *(const s16x8*)&sA[lix(mi*16 + lr, k0)];
    #pragma unroll
    for (int rr = 0; rr < 4; ++rr){
      s16x8 fQ = *(const s16x8*)&sQ[rr][lix(wn0 + lr, k0)];
      #pragma unroll
      for (int mi = 0; mi < 4; ++mi)
        acc[rr][mi] = __builtin_amdgcn_mfma_f32_16x16x32_bf16(fQ, fA[mi], acc[rr][mi], 0, 0, 0);
    }
  }

  float ls = lsp[0], lb = lbp[0];
  #pragma unroll
  for (int rr = 0; rr < 4; ++rr){
    int n1 = np*4 + rr;
    size_t rowbase = ((size_t)(bz*NH + n1)*NW)*NMED + (size_t)cs*64;
    int c0 = wn0 + kg*4;
    float4 bs4 = *(const float4*)&bnsc[cs*64 + c0];
    float4 bh4 = *(const float4*)&bnsh[cs*64 + c0];
    #pragma unroll
    for (int mi = 0; mi < 4; ++mi){
      int w = mi*16 + lr;
      if (w < 56){
        size_t oi = rowbase + (size_t)w*NMED + c0;
        ushort4 l4 = *(const ushort4*)&locraw[oi];
        float lv, rl, loc;
        ushort4 ov;
        lv = fmaf(bf2f(l4.x), bs4.x, bh4.x); rl = fmaxf(lv, 0.f); loc = fmaf(ls*rl, rl, lb);
        ov.x = f2bf(acc[rr][mi][0] + loc);
        lv = fmaf(bf2f(l4.y), bs4.y, bh4.y); rl = fmaxf(lv, 0.f); loc = fmaf(ls*rl, rl, lb);
        ov.y = f2bf(acc[rr][mi][1] + loc);
        lv = fmaf(bf2f(l4.z), bs4.z, bh4.z); rl = fmaxf(lv, 0.f); loc = fmaf(ls*rl, rl, lb);
        ov.z = f2bf(acc[rr][mi][2] + loc);
        lv = fmaf(bf2f(l4.w), bs4.w, bh4.w); rl = fmaxf(lv, 0.f); loc = fmaf(ls*rl, rl, lb);
        ov.w = f2bf(acc[rr][mi][3] + loc);
        *(ushort4*)&sbuf[oi] = ov;
      }
    }
  }
}

// ---------------- host launch ----------------

extern "C" void kernel_launch(void* const* d_in, const int* in_sizes, int n_in,
                              void* d_out, int out_size, void* d_ws, size_t ws_size,
                              hipStream_t stream){
  const float* x       = (const float*)d_in[0];
  const float* w_pw1   = (const float*)d_in[1];
  const float* w_pw2   = (const float*)d_in[2];
  const float* a1s     = (const float*)d_in[3];
  const float* a1b     = (const float*)d_in[4];
  const float* w_r1    = (const float*)d_in[5];
  const float* r_s     = (const float*)d_in[6];
  const float* r_b     = (const float*)d_in[7];
  const float* w_r2    = (const float*)d_in[8];
  const float* dwk     = (const float*)d_in[9];
  const float* dwb     = (const float*)d_in[10];
  const float* bng     = (const float*)d_in[11];
  const float* bnb     = (const float*)d_in[12];
  const float* l_s     = (const float*)d_in[13];
  const float* l_b     = (const float*)d_in[14];
  const float* cw      = (const float*)d_in[15];
  float* out = (float*)d_out;

  char* ws = (char*)d_ws;
  size_t off = 0;
  auto al = [&](size_t n)->size_t{ off = (off + 255) & ~(size_t)255; size_t r = off; off += n; return r; };
  size_t o_gE  = al((size_t)64*64*2);
  size_t o_gC  = al((size_t)64*64*2);
  size_t o_gS  = al((size_t)64*64*2);
  size_t o_gAB = al((size_t)64*64*2);
  size_t o_wT1 = al((size_t)NMED*NDIM*2);
  size_t o_wT2 = al((size_t)NDIM*NMED*2);
  size_t o_xbf = al((size_t)NPIX*NDIM*2);
  size_t o_gp  = al((size_t)NB*NH*NDIM*4);
  size_t o_g   = al((size_t)NB*NDIM*4);
  size_t o_h   = al((size_t)NB*NRH*4);
  size_t o_rt  = al((size_t)NB*NFIL*NMED*4);
  size_t o_ps  = al((size_t)NB*NH*2*NMED*4);
  size_t o_pq  = al((size_t)NB*NH*2*NMED*4);
  size_t o_p2s = al((size_t)32*NMED*4);
  size_t o_p2q = al((size_t)32*NMED*4);
  size_t o_bs  = al((size_t)NMED*4);
  size_t o_bh  = al((size_t)NMED*4);
  size_t o_v   = al((size_t)NPIX*NMED*2);

  const size_t a1_per_batch = (size_t)NWF*NH*NMED*4;
  int CH = 16;
  size_t o_A1 = 0, need = 0;
  for (;;){
    size_t o2 = off;
    auto al2 = [&](size_t n)->size_t{ o2 = (o2 + 255) & ~(size_t)255; size_t r = o2; o2 += n; return r; };
    o_A1 = al2((size_t)CH*a1_per_batch);
    need = o2;
    if (need <= ws_size || CH == 1) break;
    CH >>= 1;
  }
  if (need > ws_size) return;

  u16* gE  = (u16*)(ws + o_gE);
  u16* gC  = (u16*)(ws + o_gC);
  u16* gS  = (u16*)(ws + o_gS);
  u16* gAB = (u16*)(ws + o_gAB);
  u16* wT1 = (u16*)(ws + o_wT1);
  u16* wT2 = (u16*)(ws + o_wT2);
  u16* xbf = (u16*)(ws + o_xbf);
  float* gp = (float*)(ws + o_gp);
  float* g  = (float*)(ws + o_g);
  float* hb = (float*)(ws + o_h);
  float* rt = (float*)(ws + o_rt);
  float* ps = (float*)(ws + o_ps);
  float* pq = (float*)(ws + o_pq);
  float* p2s = (float*)(ws + o_p2s);
  float* p2q = (float*)(ws + o_p2q);
  float* bs = (float*)(ws + o_bs);
  float* bh = (float*)(ws + o_bh);
  u16* v   = (u16*)(ws + o_v);
  u32* A1p = (u32*)(ws + o_A1);
  u16* lraw = (u16*)d_out;

  k_prep<<<4, 256, 0, stream>>>(gE, gC, gS, gAB);
  k_wt<<<(NDIM*NMED+255)/256, 256, 0, stream>>>(w_pw1, wT1, NDIM, NMED);
  k_wt<<<(NMED*NDIM+255)/256, 256, 0, stream>>>(w_pw2, wT2, NMED, NDIM);

  // gpart streams x once: computes GAP partials AND writes bf16 copy of x
  k_gpart<<<dim3(NH, NB), 384, 0, stream>>>(x, gp, xbf);
  k_gfinal<<<NB, 384, 0, stream>>>(gp, g);
  k_rmlp1<<<NB, 128, 0, stream>>>(g, w_r1, r_s, r_b, hb);
  k_rmlp2<<<dim3(NMED/256, NB), 256, 0, stream>>>(hb, w_r2, rt);

  // v = StarReLU(x @ w_pw1): global_load_lds GEMM on bf16 A
  gemm_glds<0><<<dim3(NMED/128, NPIX/128), 256, 0, stream>>>(xbf, wT1, nullptr, v,
      NPIX, NMED, NDIM, a1s, a1b);

  k_dwconv<<<dim3(2, NH, NB), 192, 0, stream>>>(v, dwk, dwb, lraw, ps, pq);
  k_bnpart<<<(32*NMED)/256, 256, 0, stream>>>(ps, pq, p2s, p2q);
  k_bnfinal<<<3, 256, 0, stream>>>(p2s, p2q, bng, bnb, bs, bh);

  for (int b0 = 0; b0 < NB; b0 += CH){
    size_t pixoff = (size_t)b0*NH*NW*NMED;
    k_fftw_mfma <<<dim3(NMED/128, NH/2, CH), 256, 0, stream>>>(v + pixoff, A1p, gE);
    k_ffth_fused<<<dim3(NMED/64,  NWF,  CH), 256, 0, stream>>>(A1p, gC, gS,
                                                               rt + (size_t)b0*NFIL*NMED, cw);
    k_ifftw_mfma<<<dim3(NMED/64,  NH/4, CH), 256, 0, stream>>>(A1p, gAB, lraw + pixoff, bs, bh,
                                                               l_s, l_b, v + pixoff);
  }

  // out = (y + loc) @ w_pw2: A (=v) already bf16 -> global_load_lds GEMM
  gemm_glds<1><<<dim3(NDIM/128, NPIX/128), 256, 0, stream>>>(v, wT2, out, nullptr,
      NPIX, NDIM, NMED, nullptr, nullptr);
}

// Round 23
// 439.857 us; speedup vs baseline: 1.0158x; 1.0158x over previous
//
#include <hip/hip_runtime.h>
#include <hip/hip_bf16.h>
#include <cstdint>
#include <cstddef>

typedef unsigned short u16;
typedef unsigned int u32;
using f32x4 = __attribute__((ext_vector_type(4))) float;
using s16x8 = __attribute__((ext_vector_type(8))) short;

#define NB   16
#define NH   56
#define NW   56
#define NDIM 384
#define NMED 768
#define NFIL 4
#define NRH  96
#define NWF  29
#define NPIX (NB*NH*NW)   // 50176

__device__ __forceinline__ float bf2f(u16 u){
  union { float f; u32 i; } w; w.i = ((u32)u) << 16; return w.f;
}
__device__ __forceinline__ u16 f2bf(float f){
  union { float f; u32 i; } w; w.f = f;
  u32 i = w.i;
  return (u16)((i + 0x7fffu + ((i >> 16) & 1u)) >> 16);
}
__device__ __forceinline__ u32 packbf(float r, float i){
  return (u32)f2bf(r) | ((u32)f2bf(i) << 16);
}
// swizzled LDS index for [row][col64] bf16 tiles (breaks 128B-stride bank conflicts)
__device__ __forceinline__ int lix(int row, int col){
  return (row*64 + col) ^ ((row & 7) << 3);
}

#define GLD16(gp, lp) __builtin_amdgcn_global_load_lds( \
    (const __attribute__((address_space(1))) void*)(gp), \
    (__attribute__((address_space(3))) void*)(lp), 16, 0, 0)

// ---------------- precompute bf16 twiddle matrix images (pre-swizzled LDS layout) ----
__global__ __launch_bounds__(256) void k_prep(u16* gE, u16* gC, u16* gS, u16* gAB){
  int mat = blockIdx.x;
  int t = threadIdx.x;
  int row = t >> 2, cb = (t & 3)*16;
  const float PI2 = 6.28318530717958647692f;
  u16* dst = (mat==0) ? gE : (mat==1) ? gC : (mat==2) ? gS : gAB;
  #pragma unroll
  for (int q = 0; q < 4; ++q){
    ushort4 v4;
    #pragma unroll
    for (int m = 0; m < 4; ++m){
      int col = cb + q*4 + m;
      float val = 0.f;
      if (mat == 0){
        int k2 = row >> 1, w = col;
        if (k2 < NWF && w < 56){
          float a = PI2 * (float)((k2*w) % 56) * (1.0f/56.0f);
          val = (row & 1) ? -sinf(a) : cosf(a);
        }
      } else if (mat <= 2){
        if (row < 56 && col < 56){
          float a = PI2 * (float)((row*col) % 56) * (1.0f/56.0f);
          val = (mat == 1) ? cosf(a) : sinf(a);
        }
      } else {
        int w = row, k2 = col >> 1;
        if (w < 56 && k2 < NWF){
          float al, be;
          if (k2 == 0)       { al = 1.0f; be = 0.0f; }
          else if (k2 == 28) { al = (w & 1) ? -1.0f : 1.0f; be = 0.0f; }
          else {
            float a = PI2 * (float)((k2*w) % 56) * (1.0f/56.0f);
            al = 2.0f*cosf(a); be = -2.0f*sinf(a);
          }
          val = (col & 1) ? be : al;
        }
      }
      ((u16*)&v4)[m] = f2bf(val);
    }
    *(ushort4*)&dst[lix(row, cb + q*4)] = v4;
  }
}

__global__ __launch_bounds__(256) void k_wt(const float* __restrict__ w, u16* __restrict__ wt, int K, int N){
  int i = blockIdx.x*256 + threadIdx.x;
  if (i >= K*N) return;
  int k = i / N, n = i % N;
  wt[(size_t)n*K + k] = f2bf(w[i]);
}

// ---------------- routing (gpart also emits bf16 copy of x) ----------------

__global__ __launch_bounds__(384) void k_gpart(const float* __restrict__ x, float* __restrict__ gp,
    u16* __restrict__ xbf){
  int d = threadIdx.x, h = blockIdx.x, b = blockIdx.y;
  size_t base = ((size_t)(b*NH + h)*NW)*NDIM + d;
  const float* xp = x + base;
  u16* xo = xbf + base;
  float s = 0.f;
  for (int w = 0; w < NW; ++w){
    float f = xp[(size_t)w*NDIM];
    s += f;
    xo[(size_t)w*NDIM] = f2bf(f);
  }
  gp[(size_t)(b*NH + h)*NDIM + d] = s;
}

__global__ __launch_bounds__(384) void k_gfinal(const float* __restrict__ gp, float* __restrict__ g){
  int d = threadIdx.x, b = blockIdx.x;
  float s = 0.f;
  for (int h = 0; h < NH; ++h) s += gp[(size_t)(b*NH + h)*NDIM + d];
  g[b*NDIM + d] = s * (1.0f/3136.0f);
}

__global__ __launch_bounds__(128) void k_rmlp1(const float* __restrict__ g,
    const float* __restrict__ w_r1, const float* __restrict__ rs, const float* __restrict__ rb,
    float* __restrict__ hbuf){
  int b = blockIdx.x, t = threadIdx.x;
  __shared__ float lg[NDIM];
  for (int i = t; i < NDIM; i += 128) lg[i] = g[b*NDIM + i];
  __syncthreads();
  if (t < NRH){
    float a = 0.f;
    #pragma unroll 8
    for (int d = 0; d < NDIM; ++d) a = fmaf(lg[d], w_r1[d*NRH + t], a);
    float r = fmaxf(a, 0.f);
    hbuf[b*NRH + t] = rs[0]*r*r + rb[0];
  }
}

__global__ __launch_bounds__(256) void k_rmlp2(const float* __restrict__ hbuf,
    const float* __restrict__ w_r2, float* __restrict__ rout){
  int b = blockIdx.y;
  int c = blockIdx.x*256 + threadIdx.x;
  __shared__ float lh[NRH];
  if (threadIdx.x < NRH) lh[threadIdx.x] = hbuf[b*NRH + threadIdx.x];
  __syncthreads();
  float a0 = 0.f, a1 = 0.f, a2 = 0.f, a3 = 0.f;
  #pragma unroll 4
  for (int i = 0; i < NRH; ++i){
    float hv = lh[i];
    const float* wp = w_r2 + (size_t)i*(NFIL*NMED) + c;
    a0 = fmaf(hv, wp[0*NMED], a0);
    a1 = fmaf(hv, wp[1*NMED], a1);
    a2 = fmaf(hv, wp[2*NMED], a2);
    a3 = fmaf(hv, wp[3*NMED], a3);
  }
  float m = fmaxf(fmaxf(a0, a1), fmaxf(a2, a3));
  float e0 = expf(a0-m), e1 = expf(a1-m), e2 = expf(a2-m), e3 = expf(a3-m);
  float inv = 1.0f/(e0+e1+e2+e3);
  rout[(b*NFIL+0)*NMED + c] = e0*inv;
  rout[(b*NFIL+1)*NMED + c] = e1*inv;
  rout[(b*NFIL+2)*NMED + c] = e2*inv;
  rout[(b*NFIL+3)*NMED + c] = e3*inv;
}

// ---------------- bf16 MFMA GEMM (global_load_lds staged; bf16 A) ----------
template<int EPI>
__global__ __launch_bounds__(256) void gemm_glds(const u16* __restrict__ A, const u16* __restrict__ BT,
    float* __restrict__ Cf, u16* __restrict__ Cb, int M, int N, int K,
    const float* __restrict__ scp, const float* __restrict__ bip){
  __shared__ __align__(16) u16 lA[128*32];
  __shared__ __align__(16) u16 lB[128*32];
  int t = threadIdx.x;

  int bid = blockIdx.y * gridDim.x + blockIdx.x;
  int nwg = gridDim.x * gridDim.y;
  int q8 = nwg >> 3, r8 = nwg & 7;
  int xcd = bid & 7, idx = bid >> 3;
  int swz = (xcd < r8 ? xcd*(q8+1) : r8*(q8+1) + (xcd-r8)*q8) + idx;
  int m0 = (swz / gridDim.x) * 128;
  int n0 = (swz % gridDim.x) * 128;

  int lane = t & 63, wid = t >> 6;
  int wr = (wid >> 1) * 64, wc = (wid & 1) * 64;
  int lr = lane & 15, kg = lane >> 4;
  f32x4 acc[4][4] = {};

  int srow0 = (lane >> 2);
  int scol  = (lane & 3) * 8;

  for (int k0 = 0; k0 < K; k0 += 32){
    #pragma unroll
    for (int j = 0; j < 2; ++j){
      int row = (wid*2 + j)*16 + srow0;
      GLD16(&A [(size_t)(m0+row)*K + k0 + scol], &lA[row*32 + scol]);
      GLD16(&BT[(size_t)(n0+row)*K + k0 + scol], &lB[row*32 + scol]);
    }
    __syncthreads();
    s16x8 af[4], bf[4];
    #pragma unroll
    for (int fm = 0; fm < 4; ++fm) af[fm] = *(const s16x8*)(&lA[(wr + fm*16 + lr)*32 + kg*8]);
    #pragma unroll
    for (int fn = 0; fn < 4; ++fn) bf[fn] = *(const s16x8*)(&lB[(wc + fn*16 + lr)*32 + kg*8]);
    #pragma unroll
    for (int fm = 0; fm < 4; ++fm)
      #pragma unroll
      for (int fn = 0; fn < 4; ++fn)
        acc[fm][fn] = __builtin_amdgcn_mfma_f32_16x16x32_bf16(af[fm], bf[fn], acc[fm][fn], 0, 0, 0);
    __syncthreads();
  }

  float sc = 0.f, bi = 0.f;
  if (EPI == 0){ sc = scp[0]; bi = bip[0]; }
  #pragma unroll
  for (int fm = 0; fm < 4; ++fm)
    #pragma unroll
    for (int fn = 0; fn < 4; ++fn)
      #pragma unroll
      for (int r = 0; r < 4; ++r){
        int gm = m0 + wr + fm*16 + kg*4 + r;
        int gn = n0 + wc + fn*16 + lr;
        float val = acc[fm][fn][r];
        if (EPI == 0){
          float rl = fmaxf(val, 0.f);
          val = fmaf(sc*rl, rl, bi);
          Cb[(size_t)gm*N + gn] = f2bf(val);
        } else {
          Cf[(size_t)gm*N + gn] = val;
        }
      }
}

// ---------------- depthwise 3x3 conv + BN partials ----------------
// v3: XCD-contiguous block swizzle + x-unroll-by-2 with 2-column prefetch.
// grid (2, NH, NB) x 192 thr; psum/psq indexed [(b*NH+y)*2+seg].

__global__ __launch_bounds__(192) void k_dwconv(const u16* __restrict__ v, const float* __restrict__ kw,
    const float* __restrict__ kb, u16* __restrict__ locraw,
    float* __restrict__ psum, float* __restrict__ psq){
  int t = threadIdx.x;
  int id = blockIdx.x + 2*(blockIdx.y + (int)(56*blockIdx.z));
  int swz = (id & 7)*224 + (id >> 3);
  int seg = swz & 1;
  int y   = (swz >> 1) % 56;
  int b   = swz / 112;

  int c = t*4;
  float kk[3][3][4];
  #pragma unroll
  for (int r = 0; r < 3; ++r)
    #pragma unroll
    for (int s = 0; s < 3; ++s)
      #pragma unroll
      for (int q = 0; q < 4; ++q)
        kk[r][s][q] = kw[(r*3+s)*NMED + c + q];
  float bias[4];
  #pragma unroll
  for (int q = 0; q < 4; ++q) bias[q] = kb[c + q];

  bool vr0 = (y > 0), vr2 = (y < NH-1);
  const u16* r0 = v + ((size_t)((b*NH + y-1)*NW))*NMED + c;
  const u16* r1 = v + ((size_t)((b*NH + y  )*NW))*NMED + c;
  const u16* r2 = v + ((size_t)((b*NH + y+1)*NW))*NMED + c;

  auto LD = [&](const u16* rp, bool ok, int x, float o[4]){
    if (ok && (unsigned)x < (unsigned)NW){
      ushort4 u = *(const ushort4*)&rp[(size_t)x*NMED];
      o[0]=bf2f(u.x); o[1]=bf2f(u.y); o[2]=bf2f(u.z); o[3]=bf2f(u.w);
    } else { o[0]=0.f; o[1]=0.f; o[2]=0.f; o[3]=0.f; }
  };
  auto LD3 = [&](int x, float col[3][4]){
    LD(r0, vr0, x, col[0]); LD(r1, true, x, col[1]); LD(r2, vr2, x, col[2]);
  };

  int x0 = seg*28;
  float c0[3][4], c1[3][4], c2[3][4], c3[3][4];
  LD3(x0-1, c0); LD3(x0, c1); LD3(x0+1, c2); LD3(x0+2, c3);

  float sum[4] = {0,0,0,0}, sq[4] = {0,0,0,0};
  u16* op = locraw + ((size_t)(b*NH + y)*NW)*NMED + c;

  for (int x = x0; x < x0+28; x += 2){
    float n0[3][4], n1[3][4];
    LD3(x+3, n0); LD3(x+4, n1);

    float o0[4], o1[4];
    #pragma unroll
    for (int q = 0; q < 4; ++q){
      float t0 = bias[q];
      t0 = fmaf(c0[0][q], kk[0][0][q], t0);
      t0 = fmaf(c1[0][q], kk[0][1][q], t0);
      t0 = fmaf(c2[0][q], kk[0][2][q], t0);
      t0 = fmaf(c0[1][q], kk[1][0][q], t0);
      t0 = fmaf(c1[1][q], kk[1][1][q], t0);
      t0 = fmaf(c2[1][q], kk[1][2][q], t0);
      t0 = fmaf(c0[2][q], kk[2][0][q], t0);
      t0 = fmaf(c1[2][q], kk[2][1][q], t0);
      t0 = fmaf(c2[2][q], kk[2][2][q], t0);
      o0[q] = t0;
      sum[q] += t0; sq[q] = fmaf(t0, t0, sq[q]);
      float t1 = bias[q];
      t1 = fmaf(c1[0][q], kk[0][0][q], t1);
      t1 = fmaf(c2[0][q], kk[0][1][q], t1);
      t1 = fmaf(c3[0][q], kk[0][2][q], t1);
      t1 = fmaf(c1[1][q], kk[1][0][q], t1);
      t1 = fmaf(c2[1][q], kk[1][1][q], t1);
      t1 = fmaf(c3[1][q], kk[1][2][q], t1);
      t1 = fmaf(c1[2][q], kk[2][0][q], t1);
      t1 = fmaf(c2[2][q], kk[2][1][q], t1);
      t1 = fmaf(c3[2][q], kk[2][2][q], t1);
      o1[q] = t1;
      sum[q] += t1; sq[q] = fmaf(t1, t1, sq[q]);
    }
    ushort4 ov0, ov1;
    ov0.x = f2bf(o0[0]); ov0.y = f2bf(o0[1]); ov0.z = f2bf(o0[2]); ov0.w = f2bf(o0[3]);
    ov1.x = f2bf(o1[0]); ov1.y = f2bf(o1[1]); ov1.z = f2bf(o1[2]); ov1.w = f2bf(o1[3]);
    *(ushort4*)&op[(size_t)x*NMED]     = ov0;
    *(ushort4*)&op[(size_t)(x+1)*NMED] = ov1;
    #pragma unroll
    for (int r = 0; r < 3; ++r)
      #pragma unroll
      for (int q = 0; q < 4; ++q){
        c0[r][q] = c2[r][q]; c1[r][q] = c3[r][q];
        c2[r][q] = n0[r][q]; c3[r][q] = n1[r][q];
      }
  }
  size_t pbase = ((size_t)((b*NH + y)*2 + seg))*NMED + c;
  float4 s4; s4.x=sum[0]; s4.y=sum[1]; s4.z=sum[2]; s4.w=sum[3];
  float4 q4; q4.x=sq[0];  q4.y=sq[1];  q4.z=sq[2];  q4.w=sq[3];
  *(float4*)&psum[pbase] = s4;
  *(float4*)&psq[pbase]  = q4;
}

// ---- BN reduction, two-stage parallel ----
__global__ __launch_bounds__(256) void k_bnpart(const float* __restrict__ psum, const float* __restrict__ psq,
    float* __restrict__ ps2, float* __restrict__ pq2){
  int idx = blockIdx.x*256 + threadIdx.x;
  int c  = idx % NMED;
  int jl = idx / NMED;
  float s = 0.f, q = 0.f;
  #pragma unroll
  for (int i = 0; i < (NB*NH*2)/32; ++i){
    int j = jl + i*32;
    s += psum[(size_t)j*NMED + c];
    q += psq [(size_t)j*NMED + c];
  }
  ps2[(size_t)jl*NMED + c] = s;
  pq2[(size_t)jl*NMED + c] = q;
}

__global__ __launch_bounds__(256) void k_bnfinal(const float* __restrict__ ps2, const float* __restrict__ pq2,
    const float* __restrict__ gamma, const float* __restrict__ beta,
    float* __restrict__ bnsc, float* __restrict__ bnsh){
  int c = blockIdx.x*256 + threadIdx.x;
  if (c >= NMED) return;
  float s = 0.f, q = 0.f;
  #pragma unroll 8
  for (int j = 0; j < 32; ++j){ s += ps2[(size_t)j*NMED + c]; q += pq2[(size_t)j*NMED + c]; }
  float mu  = s * (1.0f/(float)NPIX);
  float var = q * (1.0f/(float)NPIX) - mu*mu;
  float sc = gamma[c] * rsqrtf(var + 1e-5f);
  bnsc[c] = sc;
  bnsh[c] = beta[c] - mu*sc;
}

// ---------------- spectral stages (all MFMA) ----------------
// A1p packs (re,im) bf16 into one u32 per element: lo16=re, hi16=im.

// forward rDFT along W, 2 h-rows per block (E fragments reused across rows).
__global__ __launch_bounds__(256) void k_fftw_mfma(const u16* __restrict__ v,
    u32* __restrict__ A1p, const u16* __restrict__ gE){
  __shared__ u16 sE[64*64];        // 8 KB
  __shared__ u16 sV[2][128*64];    // 32 KB
  int t = threadIdx.x;
  int cs = blockIdx.x, hp = blockIdx.y, bz = blockIdx.z;

  ((int4*)sE)[t]       = ((const int4*)gE)[t];
  ((int4*)sE)[t + 256] = ((const int4*)gE)[t + 256];

  #pragma unroll
  for (int rr = 0; rr < 2; ++rr){
    int h = hp*2 + rr;
    int cg = (t & 15) * 8;
    int wq = (t >> 4) * 4;
    u16 buf[4][8];
    #pragma unroll
    for (int dw = 0; dw < 4; ++dw){
      int w = wq + dw;
      if (w < 56){
        *(int4*)&buf[dw][0] = *(const int4*)&v[((size_t)((bz*NH + h)*NW) + w)*NMED + (size_t)cs*128 + cg];
      } else {
        #pragma unroll
        for (int j = 0; j < 8; ++j) buf[dw][j] = 0;
      }
    }
    #pragma unroll
    for (int j = 0; j < 8; ++j){
      u16 tmp[4] = {buf[0][j], buf[1][j], buf[2][j], buf[3][j]};
      *(uint2*)&sV[rr][lix(cg + j, wq)] = *(uint2*)tmp;
    }
  }
  __syncthreads();

  int lane = t & 63, wid = t >> 6;
  int lr = lane & 15, kg = lane >> 4;
  int wn0 = wid * 32;
  f32x4 acc[2][4][2] = {};

  #pragma unroll
  for (int ks = 0; ks < 2; ++ks){
    int k0 = ks*32 + kg*8;
    s16x8 fE[4];
    #pragma unroll
    for (int mi = 0; mi < 4; ++mi) fE[mi] = *(const s16x8*)&sE[lix(mi*16 + lr, k0)];
    #pragma unroll
    for (int rr = 0; rr < 2; ++rr){
      #pragma unroll
      for (int ni = 0; ni < 2; ++ni){
        s16x8 bv = *(const s16x8*)&sV[rr][lix(wn0 + ni*16 + lr, k0)];
        #pragma unroll
        for (int mi = 0; mi < 4; ++mi)
          acc[rr][mi][ni] = __builtin_amdgcn_mfma_f32_16x16x32_bf16(fE[mi], bv, acc[rr][mi][ni], 0, 0, 0);
      }
    }
  }

  #pragma unroll
  for (int rr = 0; rr < 2; ++rr){
    int h = hp*2 + rr;
    size_t gb = ((size_t)bz*NWF*NH)*NMED + (size_t)h*NMED + (size_t)cs*128;
    #pragma unroll
    for (int mi = 0; mi < 4; ++mi){
      #pragma unroll
      for (int rp = 0; rp < 2; ++rp){
        int j0 = mi*16 + kg*4 + rp*2;
        int k2 = j0 >> 1;
        if (k2 < NWF){
          #pragma unroll
          for (int ni = 0; ni < 2; ++ni){
            int c = wn0 + ni*16 + lr;
            A1p[gb + (size_t)k2*NH*NMED + c] = packbf(acc[rr][mi][ni][rp*2], acc[rr][mi][ni][rp*2+1]);
          }
        }
      }
    }
  }
}

// Fused H-stage via MFMA, 64-channel tiles.
// P = E_f X ; P' = P .* W /3136 ; Q = E_i P'. In-place on A1p.
__global__ __launch_bounds__(256) void k_ffth_fused(u32* __restrict__ A1p,
    const u16* __restrict__ gC, const u16* __restrict__ gS,
    const float* __restrict__ rout, const float* __restrict__ cw){
  __shared__ u16 sC[64*64], sS[64*64];   // 8 KB each
  __shared__ u16 sXr[64*64], sXi[64*64]; // 8 KB each (X, then P')
  __shared__ float cwS[56*8];            // 1.8 KB -> total ~34 KB
  int t = threadIdx.x;
  int cs = blockIdx.x, k2 = blockIdx.y, bz = blockIdx.z;
  size_t gbase = ((size_t)(bz*NWF + k2)*NH)*NMED + (size_t)cs*64;

  ((int4*)sC)[t]       = ((const int4*)gC)[t];
  ((int4*)sC)[t + 256] = ((const int4*)gC)[t + 256];
  ((int4*)sS)[t]       = ((const int4*)gS)[t];
  ((int4*)sS)[t + 256] = ((const int4*)gS)[t + 256];

  for (int j = t; j < 56*8; j += 256){
    int k1 = j >> 3, f = j & 7;
    cwS[j] = cw[((size_t)(k1*NWF + k2))*8 + f];
  }
  {
    int c = t & 63;
    int hg = t >> 6;
    #pragma unroll
    for (int q = 0; q < 4; ++q){
      int h = hg*16 + q*4;
      u32 u0=0, u1=0, u2=0, u3=0;
      if (h < 56){
        const u32* gp = &A1p[gbase + (size_t)h*NMED + c];
        u0 = gp[0*NMED]; u1 = gp[1*NMED]; u2 = gp[2*NMED]; u3 = gp[3*NMED];
      }
      uint2 rr, ii;
      rr.x = (u0 & 0xffffu) | (u1 << 16);
      rr.y = (u2 & 0xffffu) | (u3 << 16);
      ii.x = (u0 >> 16) | (u1 & 0xffff0000u);
      ii.y = (u2 >> 16) | (u3 & 0xffff0000u);
      *(uint2*)&sXr[lix(c, h)] = rr;
      *(uint2*)&sXi[lix(c, h)] = ii;
    }
  }
  __syncthreads();

  int lane = t & 63, wid = t >> 6;
  int lr = lane & 15, kg = lane >> 4;
  int wn0 = wid * 16;                 // 4 waves x 16 channels = 64

  f32x4 aR[4], aI[4];
  #pragma unroll
  for (int mi = 0; mi < 4; ++mi){ aR[mi] = (f32x4){0,0,0,0}; aI[mi] = (f32x4){0,0,0,0}; }

  #pragma unroll
  for (int ks = 0; ks < 2; ++ks){
    int k0 = ks*32 + kg*8;
    s16x8 fC[4], fS[4];
    #pragma unroll
    for (int mi = 0; mi < 4; ++mi){
      fC[mi] = *(const s16x8*)&sC[lix(mi*16 + lr, k0)];
      fS[mi] = *(const s16x8*)&sS[lix(mi*16 + lr, k0)];
    }
    s16x8 xr = *(const s16x8*)&sXr[lix(wn0 + lr, k0)];
    s16x8 xi = *(const s16x8*)&sXi[lix(wn0 + lr, k0)];
    uint4 xu = *(uint4*)&xr;
    xu.x ^= 0x80008000u; xu.y ^= 0x80008000u; xu.z ^= 0x80008000u; xu.w ^= 0x80008000u;
    s16x8 xrn = *(s16x8*)&xu;
    #pragma unroll
    for (int mi = 0; mi < 4; ++mi){
      aR[mi] = __builtin_amdgcn_mfma_f32_16x16x32_bf16(fC[mi], xr,  aR[mi], 0,0,0);
      aR[mi] = __builtin_amdgcn_mfma_f32_16x16x32_bf16(fS[mi], xi,  aR[mi], 0,0,0);
      aI[mi] = __builtin_amdgcn_mfma_f32_16x16x32_bf16(fC[mi], xi,  aI[mi], 0,0,0);
      aI[mi] = __builtin_amdgcn_mfma_f32_16x16x32_bf16(fS[mi], xrn, aI[mi], 0,0,0);
    }
  }
  __syncthreads();

  const float inv = 1.0f/3136.0f;
  float rv0, rv1, rv2, rv3;
  {
    int cg = cs*64 + wn0 + lr;
    rv0 = rout[(bz*NFIL+0)*NMED + cg];
    rv1 = rout[(bz*NFIL+1)*NMED + cg];
    rv2 = rout[(bz*NFIL+2)*NMED + cg];
    rv3 = rout[(bz*NFIL+3)*NMED + cg];
  }
  #pragma unroll
  for (int mi = 0; mi < 4; ++mi){
    #pragma unroll
    for (int r = 0; r < 4; ++r){
      int k1 = mi*16 + kg*4 + r;
      float c0=0,c1=0,c2=0,c3=0,c4=0,c5=0,c6=0,c7=0;
      if (k1 < 56){
        const float* cp = cwS + k1*8;
        c0=cp[0]; c1=cp[1]; c2=cp[2]; c3=cp[3]; c4=cp[4]; c5=cp[5]; c6=cp[6]; c7=cp[7];
      }
      float wr = rv0*c0 + rv1*c2 + rv2*c4 + rv3*c6;
      float wi = rv0*c1 + rv1*c3 + rv2*c5 + rv3*c7;
      float pr = aR[mi][r], pi = aI[mi][r];
      float qr = (pr*wr - pi*wi) * inv;
      float qi = (pr*wi + pi*wr) * inv;
      int cl = wn0 + lr;
      sXr[lix(cl, k1)] = f2bf(qr);
      sXi[lix(cl, k1)] = f2bf(qi);
    }
  }
  __syncthreads();

  #pragma unroll
  for (int mi = 0; mi < 4; ++mi){ aR[mi] = (f32x4){0,0,0,0}; aI[mi] = (f32x4){0,0,0,0}; }
  #pragma unroll
  for (int ks = 0; ks < 2; ++ks){
    int k0 = ks*32 + kg*8;
    s16x8 fC[4], fS[4];
    #pragma unroll
    for (int mi = 0; mi < 4; ++mi){
      fC[mi] = *(const s16x8*)&sC[lix(mi*16 + lr, k0)];
      fS[mi] = *(const s16x8*)&sS[lix(mi*16 + lr, k0)];
    }
    s16x8 pr = *(const s16x8*)&sXr[lix(wn0 + lr, k0)];
    s16x8 pi = *(const s16x8*)&sXi[lix(wn0 + lr, k0)];
    uint4 pu = *(uint4*)&pi;
    pu.x ^= 0x80008000u; pu.y ^= 0x80008000u; pu.z ^= 0x80008000u; pu.w ^= 0x80008000u;
    s16x8 pin = *(s16x8*)&pu;
    #pragma unroll
    for (int mi = 0; mi < 4; ++mi){
      aR[mi] = __builtin_amdgcn_mfma_f32_16x16x32_bf16(fC[mi], pr,  aR[mi], 0,0,0);
      aR[mi] = __builtin_amdgcn_mfma_f32_16x16x32_bf16(fS[mi], pin, aR[mi], 0,0,0);
      aI[mi] = __builtin_amdgcn_mfma_f32_16x16x32_bf16(fC[mi], pi,  aI[mi], 0,0,0);
      aI[mi] = __builtin_amdgcn_mfma_f32_16x16x32_bf16(fS[mi], pr,  aI[mi], 0,0,0);
    }
  }

  #pragma unroll
  for (int mi = 0; mi < 4; ++mi){
    #pragma unroll
    for (int r = 0; r < 4; ++r){
      int n1 = mi*16 + kg*4 + r;
      if (n1 < 56){
        int cl = wn0 + lr;
        A1p[gbase + (size_t)n1*NMED + cl] = packbf(aR[mi][r], aI[mi][r]);
      }
    }
  }
}

// inverse along W via MFMA, 64-channel tiles, 2 n1-rows per block.
// Swapped operands: output fragment row=channel (4 consecutive/lane), col=w.
__global__ __launch_bounds__(256) void k_ifftw_mfma(const u32* __restrict__ Qp,
    const u16* __restrict__ gAB, const u16* __restrict__ locraw,
    const float* __restrict__ bnsc, const float* __restrict__ bnsh,
    const float* __restrict__ lsp, const float* __restrict__ lbp, u16* __restrict__ sbuf){
  __shared__ u16 sA[64*64];       // 8 KB
  __shared__ u16 sQ[2][64*64];    // 16 KB -> total 24 KB
  int t = threadIdx.x;
  int cs = blockIdx.x, np = blockIdx.y, bz = blockIdx.z;

  ((int4*)sA)[t]       = ((const int4*)gAB)[t];
  ((int4*)sA)[t + 256] = ((const int4*)gAB)[t + 256];

  {
    int c = t & 63;
    int g = t >> 6;
    #pragma unroll
    for (int rr = 0; rr < 2; ++rr){
      int n1 = np*2 + rr;
      size_t qb = (((size_t)bz*NWF)*NH + n1)*NMED + (size_t)cs*64 + c;
      u32 qv[8];
      #pragma unroll
      for (int i = 0; i < 8; ++i){
        int k2 = 4*i + g;
        qv[i] = (k2 < NWF) ? Qp[qb + (size_t)k2*NH*NMED] : 0u;
      }
      #pragma unroll
      for (int i = 0; i < 8; ++i){
        int k2 = 4*i + g;
        *(u32*)&sQ[rr][lix(c, 2*k2)] = qv[i];
      }
    }
  }
  __syncthreads();

  int lane = t & 63, wid = t >> 6;
  int lr = lane & 15, kg = lane >> 4;
  int wn0 = wid * 16;
  f32x4 acc[2][4] = {};

  #pragma unroll
  for (int ks = 0; ks < 2; ++ks){
    int k0 = ks*32 + kg*8;
    s16x8 fA[4];
    #pragma unroll
    for (int mi = 0; mi < 4; ++mi) fA[mi] = *(const s16x8*)&sA[lix(mi*16 + lr, k0)];
    #pragma unroll
    for (int rr = 0; rr < 2; ++rr){
      s16x8 fQ = *(const s16x8*)&sQ[rr][lix(wn0 + lr, k0)];
      #pragma unroll
      for (int mi = 0; mi < 4; ++mi)
        acc[rr][mi] = __builtin_amdgcn_mfma_f32_16x16x32_bf16(fQ, fA[mi], acc[rr][mi], 0, 0, 0);
    }
  }

  float ls = lsp[0], lb = lbp[0];
  #pragma unroll
  for (int rr = 0; rr < 2; ++rr){
    int n1 = np*2 + rr;
    size_t rowbase = ((size_t)(bz*NH + n1)*NW)*NMED + (size_t)cs*64;
    int c0 = wn0 + kg*4;
    float4 bs4 = *(const float4*)&bnsc[cs*64 + c0];
    float4 bh4 = *(const float4*)&bnsh[cs*64 + c0];
    #pragma unroll
    for (int mi = 0; mi < 4; ++mi){
      int w = mi*16 + lr;
      if (w < 56){
        size_t oi = rowbase + (size_t)w*NMED + c0;
        ushort4 l4 = *(const ushort4*)&locraw[oi];
        float lv, rl, loc;
        ushort4 ov;
        lv = fmaf(bf2f(l4.x), bs4.x, bh4.x); rl = fmaxf(lv, 0.f); loc = fmaf(ls*rl, rl, lb);
        ov.x = f2bf(acc[rr][mi][0] + loc);
        lv = fmaf(bf2f(l4.y), bs4.y, bh4.y); rl = fmaxf(lv, 0.f); loc = fmaf(ls*rl, rl, lb);
        ov.y = f2bf(acc[rr][mi][1] + loc);
        lv = fmaf(bf2f(l4.z), bs4.z, bh4.z); rl = fmaxf(lv, 0.f); loc = fmaf(ls*rl, rl, lb);
        ov.z = f2bf(acc[rr][mi][2] + loc);
        lv = fmaf(bf2f(l4.w), bs4.w, bh4.w); rl = fmaxf(lv, 0.f); loc = fmaf(ls*rl, rl, lb);
        ov.w = f2bf(acc[rr][mi][3] + loc);
        *(ushort4*)&sbuf[oi] = ov;
      }
    }
  }
}

// ---------------- host launch ----------------

extern "C" void kernel_launch(void* const* d_in, const int* in_sizes, int n_in,
                              void* d_out, int out_size, void* d_ws, size_t ws_size,
                              hipStream_t stream){
  const float* x       = (const float*)d_in[0];
  const float* w_pw1   = (const float*)d_in[1];
  const float* w_pw2   = (const float*)d_in[2];
  const float* a1s     = (const float*)d_in[3];
  const float* a1b     = (const float*)d_in[4];
  const float* w_r1    = (const float*)d_in[5];
  const float* r_s     = (const float*)d_in[6];
  const float* r_b     = (const float*)d_in[7];
  const float* w_r2    = (const float*)d_in[8];
  const float* dwk     = (const float*)d_in[9];
  const float* dwb     = (const float*)d_in[10];
  const float* bng     = (const float*)d_in[11];
  const float* bnb     = (const float*)d_in[12];
  const float* l_s     = (const float*)d_in[13];
  const float* l_b     = (const float*)d_in[14];
  const float* cw      = (const float*)d_in[15];
  float* out = (float*)d_out;

  char* ws = (char*)d_ws;
  size_t off = 0;
  auto al = [&](size_t n)->size_t{ off = (off + 255) & ~(size_t)255; size_t r = off; off += n; return r; };
  size_t o_gE  = al((size_t)64*64*2);
  size_t o_gC  = al((size_t)64*64*2);
  size_t o_gS  = al((size_t)64*64*2);
  size_t o_gAB = al((size_t)64*64*2);
  size_t o_wT1 = al((size_t)NMED*NDIM*2);
  size_t o_wT2 = al((size_t)NDIM*NMED*2);
  size_t o_xbf = al((size_t)NPIX*NDIM*2);
  size_t o_gp  = al((size_t)NB*NH*NDIM*4);
  size_t o_g   = al((size_t)NB*NDIM*4);
  size_t o_h   = al((size_t)NB*NRH*4);
  size_t o_rt  = al((size_t)NB*NFIL*NMED*4);
  size_t o_ps  = al((size_t)NB*NH*2*NMED*4);
  size_t o_pq  = al((size_t)NB*NH*2*NMED*4);
  size_t o_p2s = al((size_t)32*NMED*4);
  size_t o_p2q = al((size_t)32*NMED*4);
  size_t o_bs  = al((size_t)NMED*4);
  size_t o_bh  = al((size_t)NMED*4);
  size_t o_v   = al((size_t)NPIX*NMED*2);

  const size_t a1_per_batch = (size_t)NWF*NH*NMED*4;
  int CH = 16;
  size_t o_A1 = 0, need = 0;
  for (;;){
    size_t o2 = off;
    auto al2 = [&](size_t n)->size_t{ o2 = (o2 + 255) & ~(size_t)255; size_t r = o2; o2 += n; return r; };
    o_A1 = al2((size_t)CH*a1_per_batch);
    need = o2;
    if (need <= ws_size || CH == 1) break;
    CH >>= 1;
  }
  if (need > ws_size) return;

  u16* gE  = (u16*)(ws + o_gE);
  u16* gC  = (u16*)(ws + o_gC);
  u16* gS  = (u16*)(ws + o_gS);
  u16* gAB = (u16*)(ws + o_gAB);
  u16* wT1 = (u16*)(ws + o_wT1);
  u16* wT2 = (u16*)(ws + o_wT2);
  u16* xbf = (u16*)(ws + o_xbf);
  float* gp = (float*)(ws + o_gp);
  float* g  = (float*)(ws + o_g);
  float* hb = (float*)(ws + o_h);
  float* rt = (float*)(ws + o_rt);
  float* ps = (float*)(ws + o_ps);
  float* pq = (float*)(ws + o_pq);
  float* p2s = (float*)(ws + o_p2s);
  float* p2q = (float*)(ws + o_p2q);
  float* bs = (float*)(ws + o_bs);
  float* bh = (float*)(ws + o_bh);
  u16* v   = (u16*)(ws + o_v);
  u32* A1p = (u32*)(ws + o_A1);
  u16* lraw = (u16*)d_out;

  k_prep<<<4, 256, 0, stream>>>(gE, gC, gS, gAB);
  k_wt<<<(NDIM*NMED+255)/256, 256, 0, stream>>>(w_pw1, wT1, NDIM, NMED);
  k_wt<<<(NMED*NDIM+255)/256, 256, 0, stream>>>(w_pw2, wT2, NMED, NDIM);

  // gpart streams x once: computes GAP partials AND writes bf16 copy of x
  k_gpart<<<dim3(NH, NB), 384, 0, stream>>>(x, gp, xbf);
  k_gfinal<<<NB, 384, 0, stream>>>(gp, g);
  k_rmlp1<<<NB, 128, 0, stream>>>(g, w_r1, r_s, r_b, hb);
  k_rmlp2<<<dim3(NMED/256, NB), 256, 0, stream>>>(hb, w_r2, rt);

  // v = StarReLU(x @ w_pw1): global_load_lds GEMM on bf16 A
  gemm_glds<0><<<dim3(NMED/128, NPIX/128), 256, 0, stream>>>(xbf, wT1, nullptr, v,
      NPIX, NMED, NDIM, a1s, a1b);

  k_dwconv<<<dim3(2, NH, NB), 192, 0, stream>>>(v, dwk, dwb, lraw, ps, pq);
  k_bnpart<<<(32*NMED)/256, 256, 0, stream>>>(ps, pq, p2s, p2q);
  k_bnfinal<<<3, 256, 0, stream>>>(p2s, p2q, bng, bnb, bs, bh);

  for (int b0 = 0; b0 < NB; b0 += CH){
    size_t pixoff = (size_t)b0*NH*NW*NMED;
    k_fftw_mfma <<<dim3(NMED/128, NH/2, CH), 256, 0, stream>>>(v + pixoff, A1p, gE);
    k_ffth_fused<<<dim3(NMED/64,  NWF,  CH), 256, 0, stream>>>(A1p, gC, gS,
                                                               rt + (size_t)b0*NFIL*NMED, cw);
    k_ifftw_mfma<<<dim3(NMED/64,  NH/2, CH), 256, 0, stream>>>(A1p, gAB, lraw + pixoff, bs, bh,
                                                               l_s, l_b, v + pixoff);
  }

  // out = (y + loc) @ w_pw2: A (=v) already bf16 -> global_load_lds GEMM
  gemm_glds<1><<<dim3(NDIM/128, NPIX/128), 256, 0, stream>>>(v, wT2, out, nullptr,
      NPIX, NDIM, NMED, nullptr, nullptr);
}

// Round 24
// 436.884 us; speedup vs baseline: 1.0227x; 1.0068x over previous
//
#include <hip/hip_runtime.h>
#include <hip/hip_bf16.h>
#include <cstdint>
#include <cstddef>

typedef unsigned short u16;
typedef unsigned int u32;
using f32x4 = __attribute__((ext_vector_type(4))) float;
using s16x8 = __attribute__((ext_vector_type(8))) short;

#define NB   16
#define NH   56
#define NW   56
#define NDIM 384
#define NMED 768
#define NFIL 4
#define NRH  96
#define NWF  29
#define NPIX (NB*NH*NW)   // 50176

__device__ __forceinline__ float bf2f(u16 u){
  union { float f; u32 i; } w; w.i = ((u32)u) << 16; return w.f;
}
__device__ __forceinline__ u16 f2bf(float f){
  union { float f; u32 i; } w; w.f = f;
  u32 i = w.i;
  return (u16)((i + 0x7fffu + ((i >> 16) & 1u)) >> 16);
}
__device__ __forceinline__ u32 packbf(float r, float i){
  return (u32)f2bf(r) | ((u32)f2bf(i) << 16);
}
// swizzled LDS index for [row][col64] bf16 tiles (breaks 128B-stride bank conflicts)
__device__ __forceinline__ int lix(int row, int col){
  return (row*64 + col) ^ ((row & 7) << 3);
}

#define GLD16(gp, lp) __builtin_amdgcn_global_load_lds( \
    (const __attribute__((address_space(1))) void*)(gp), \
    (__attribute__((address_space(3))) void*)(lp), 16, 0, 0)

// ---------------- precompute bf16 twiddle matrix images (pre-swizzled LDS layout) ----
__global__ __launch_bounds__(256) void k_prep(u16* gE, u16* gC, u16* gS, u16* gAB){
  int mat = blockIdx.x;
  int t = threadIdx.x;
  int row = t >> 2, cb = (t & 3)*16;
  const float PI2 = 6.28318530717958647692f;
  u16* dst = (mat==0) ? gE : (mat==1) ? gC : (mat==2) ? gS : gAB;
  #pragma unroll
  for (int q = 0; q < 4; ++q){
    ushort4 v4;
    #pragma unroll
    for (int m = 0; m < 4; ++m){
      int col = cb + q*4 + m;
      float val = 0.f;
      if (mat == 0){
        int k2 = row >> 1, w = col;
        if (k2 < NWF && w < 56){
          float a = PI2 * (float)((k2*w) % 56) * (1.0f/56.0f);
          val = (row & 1) ? -sinf(a) : cosf(a);
        }
      } else if (mat <= 2){
        if (row < 56 && col < 56){
          float a = PI2 * (float)((row*col) % 56) * (1.0f/56.0f);
          val = (mat == 1) ? cosf(a) : sinf(a);
        }
      } else {
        int w = row, k2 = col >> 1;
        if (w < 56 && k2 < NWF){
          float al, be;
          if (k2 == 0)       { al = 1.0f; be = 0.0f; }
          else if (k2 == 28) { al = (w & 1) ? -1.0f : 1.0f; be = 0.0f; }
          else {
            float a = PI2 * (float)((k2*w) % 56) * (1.0f/56.0f);
            al = 2.0f*cosf(a); be = -2.0f*sinf(a);
          }
          val = (col & 1) ? be : al;
        }
      }
      ((u16*)&v4)[m] = f2bf(val);
    }
    *(ushort4*)&dst[lix(row, cb + q*4)] = v4;
  }
}

__global__ __launch_bounds__(256) void k_wt(const float* __restrict__ w, u16* __restrict__ wt, int K, int N){
  int i = blockIdx.x*256 + threadIdx.x;
  if (i >= K*N) return;
  int k = i / N, n = i % N;
  wt[(size_t)n*K + k] = f2bf(w[i]);
}

// ---------------- routing (gpart also emits bf16 copy of x) ----------------

__global__ __launch_bounds__(384) void k_gpart(const float* __restrict__ x, float* __restrict__ gp,
    u16* __restrict__ xbf){
  int d = threadIdx.x, h = blockIdx.x, b = blockIdx.y;
  size_t base = ((size_t)(b*NH + h)*NW)*NDIM + d;
  const float* xp = x + base;
  u16* xo = xbf + base;
  float s = 0.f;
  for (int w = 0; w < NW; ++w){
    float f = xp[(size_t)w*NDIM];
    s += f;
    xo[(size_t)w*NDIM] = f2bf(f);
  }
  gp[(size_t)(b*NH + h)*NDIM + d] = s;
}

__global__ __launch_bounds__(384) void k_gfinal(const float* __restrict__ gp, float* __restrict__ g){
  int d = threadIdx.x, b = blockIdx.x;
  float s = 0.f;
  for (int h = 0; h < NH; ++h) s += gp[(size_t)(b*NH + h)*NDIM + d];
  g[b*NDIM + d] = s * (1.0f/3136.0f);
}

__global__ __launch_bounds__(128) void k_rmlp1(const float* __restrict__ g,
    const float* __restrict__ w_r1, const float* __restrict__ rs, const float* __restrict__ rb,
    float* __restrict__ hbuf){
  int b = blockIdx.x, t = threadIdx.x;
  __shared__ float lg[NDIM];
  for (int i = t; i < NDIM; i += 128) lg[i] = g[b*NDIM + i];
  __syncthreads();
  if (t < NRH){
    float a = 0.f;
    #pragma unroll 8
    for (int d = 0; d < NDIM; ++d) a = fmaf(lg[d], w_r1[d*NRH + t], a);
    float r = fmaxf(a, 0.f);
    hbuf[b*NRH + t] = rs[0]*r*r + rb[0];
  }
}

__global__ __launch_bounds__(256) void k_rmlp2(const float* __restrict__ hbuf,
    const float* __restrict__ w_r2, float* __restrict__ rout){
  int b = blockIdx.y;
  int c = blockIdx.x*256 + threadIdx.x;
  __shared__ float lh[NRH];
  if (threadIdx.x < NRH) lh[threadIdx.x] = hbuf[b*NRH + threadIdx.x];
  __syncthreads();
  float a0 = 0.f, a1 = 0.f, a2 = 0.f, a3 = 0.f;
  #pragma unroll 4
  for (int i = 0; i < NRH; ++i){
    float hv = lh[i];
    const float* wp = w_r2 + (size_t)i*(NFIL*NMED) + c;
    a0 = fmaf(hv, wp[0*NMED], a0);
    a1 = fmaf(hv, wp[1*NMED], a1);
    a2 = fmaf(hv, wp[2*NMED], a2);
    a3 = fmaf(hv, wp[3*NMED], a3);
  }
  float m = fmaxf(fmaxf(a0, a1), fmaxf(a2, a3));
  float e0 = expf(a0-m), e1 = expf(a1-m), e2 = expf(a2-m), e3 = expf(a3-m);
  float inv = 1.0f/(e0+e1+e2+e3);
  rout[(b*NFIL+0)*NMED + c] = e0*inv;
  rout[(b*NFIL+1)*NMED + c] = e1*inv;
  rout[(b*NFIL+2)*NMED + c] = e2*inv;
  rout[(b*NFIL+3)*NMED + c] = e3*inv;
}

// ---------------- bf16 MFMA GEMM (global_load_lds staged; bf16 A) ----------
// v2: BK=64 (half the barrier drains; 32 MFMA/wave between barriers).
// 128B-stride rows need the T2 both-sides XOR swizzle: global 16B-chunk
// index ^ (row&7) loaded into the LINEAR slot; fragment reads apply the
// same XOR -> reads spread across all 32 banks (<=2-way, free).
template<int EPI>
__global__ __launch_bounds__(256) void gemm_glds(const u16* __restrict__ A, const u16* __restrict__ BT,
    float* __restrict__ Cf, u16* __restrict__ Cb, int M, int N, int K,
    const float* __restrict__ scp, const float* __restrict__ bip){
  __shared__ __align__(16) u16 lA[128*64];
  __shared__ __align__(16) u16 lB[128*64];
  int t = threadIdx.x;

  int bid = blockIdx.y * gridDim.x + blockIdx.x;
  int nwg = gridDim.x * gridDim.y;
  int q8 = nwg >> 3, r8 = nwg & 7;
  int xcd = bid & 7, idx = bid >> 3;
  int swz = (xcd < r8 ? xcd*(q8+1) : r8*(q8+1) + (xcd-r8)*q8) + idx;
  int m0 = (swz / gridDim.x) * 128;
  int n0 = (swz % gridDim.x) * 128;

  int lane = t & 63, wid = t >> 6;
  int wr = (wid >> 1) * 64, wc = (wid & 1) * 64;
  int lr = lane & 15, kg = lane >> 4;
  f32x4 acc[4][4] = {};

  int srow0 = (lane >> 3);         // 0..7
  int scj   = (lane & 7);          // 16B chunk slot within the 128B K-row

  for (int k0 = 0; k0 < K; k0 += 64){
    #pragma unroll
    for (int j = 0; j < 4; ++j){
      int row = wid*32 + j*8 + srow0;
      int gcj = scj ^ (row & 7);   // pre-swizzled global source chunk
      GLD16(&A [(size_t)(m0+row)*K + k0 + gcj*8], &lA[row*64 + scj*8]);
      GLD16(&BT[(size_t)(n0+row)*K + k0 + gcj*8], &lB[row*64 + scj*8]);
    }
    __syncthreads();
    #pragma unroll
    for (int ks = 0; ks < 2; ++ks){
      s16x8 af[4], bf[4];
      #pragma unroll
      for (int fm = 0; fm < 4; ++fm){
        int r = wr + fm*16 + lr;
        af[fm] = *(const s16x8*)(&lA[r*64 + (((ks*4 + kg) ^ (r & 7)))*8]);
      }
      #pragma unroll
      for (int fn = 0; fn < 4; ++fn){
        int r = wc + fn*16 + lr;
        bf[fn] = *(const s16x8*)(&lB[r*64 + (((ks*4 + kg) ^ (r & 7)))*8]);
      }
      #pragma unroll
      for (int fm = 0; fm < 4; ++fm)
        #pragma unroll
        for (int fn = 0; fn < 4; ++fn)
          acc[fm][fn] = __builtin_amdgcn_mfma_f32_16x16x32_bf16(af[fm], bf[fn], acc[fm][fn], 0, 0, 0);
    }
    __syncthreads();
  }

  float sc = 0.f, bi = 0.f;
  if (EPI == 0){ sc = scp[0]; bi = bip[0]; }
  #pragma unroll
  for (int fm = 0; fm < 4; ++fm)
    #pragma unroll
    for (int fn = 0; fn < 4; ++fn)
      #pragma unroll
      for (int r = 0; r < 4; ++r){
        int gm = m0 + wr + fm*16 + kg*4 + r;
        int gn = n0 + wc + fn*16 + lr;
        float val = acc[fm][fn][r];
        if (EPI == 0){
          float rl = fmaxf(val, 0.f);
          val = fmaf(sc*rl, rl, bi);
          Cb[(size_t)gm*N + gn] = f2bf(val);
        } else {
          Cf[(size_t)gm*N + gn] = val;
        }
      }
}

// ---------------- depthwise 3x3 conv + BN partials ----------------
// v3: XCD-contiguous block swizzle + x-unroll-by-2 with 2-column prefetch.
// grid (2, NH, NB) x 192 thr; psum/psq indexed [(b*NH+y)*2+seg].

__global__ __launch_bounds__(192) void k_dwconv(const u16* __restrict__ v, const float* __restrict__ kw,
    const float* __restrict__ kb, u16* __restrict__ locraw,
    float* __restrict__ psum, float* __restrict__ psq){
  int t = threadIdx.x;
  int id = blockIdx.x + 2*(blockIdx.y + (int)(56*blockIdx.z));
  int swz = (id & 7)*224 + (id >> 3);
  int seg = swz & 1;
  int y   = (swz >> 1) % 56;
  int b   = swz / 112;

  int c = t*4;
  float kk[3][3][4];
  #pragma unroll
  for (int r = 0; r < 3; ++r)
    #pragma unroll
    for (int s = 0; s < 3; ++s)
      #pragma unroll
      for (int q = 0; q < 4; ++q)
        kk[r][s][q] = kw[(r*3+s)*NMED + c + q];
  float bias[4];
  #pragma unroll
  for (int q = 0; q < 4; ++q) bias[q] = kb[c + q];

  bool vr0 = (y > 0), vr2 = (y < NH-1);
  const u16* r0 = v + ((size_t)((b*NH + y-1)*NW))*NMED + c;
  const u16* r1 = v + ((size_t)((b*NH + y  )*NW))*NMED + c;
  const u16* r2 = v + ((size_t)((b*NH + y+1)*NW))*NMED + c;

  auto LD = [&](const u16* rp, bool ok, int x, float o[4]){
    if (ok && (unsigned)x < (unsigned)NW){
      ushort4 u = *(const ushort4*)&rp[(size_t)x*NMED];
      o[0]=bf2f(u.x); o[1]=bf2f(u.y); o[2]=bf2f(u.z); o[3]=bf2f(u.w);
    } else { o[0]=0.f; o[1]=0.f; o[2]=0.f; o[3]=0.f; }
  };
  auto LD3 = [&](int x, float col[3][4]){
    LD(r0, vr0, x, col[0]); LD(r1, true, x, col[1]); LD(r2, vr2, x, col[2]);
  };

  int x0 = seg*28;
  float c0[3][4], c1[3][4], c2[3][4], c3[3][4];
  LD3(x0-1, c0); LD3(x0, c1); LD3(x0+1, c2); LD3(x0+2, c3);

  float sum[4] = {0,0,0,0}, sq[4] = {0,0,0,0};
  u16* op = locraw + ((size_t)(b*NH + y)*NW)*NMED + c;

  for (int x = x0; x < x0+28; x += 2){
    float n0[3][4], n1[3][4];
    LD3(x+3, n0); LD3(x+4, n1);

    float o0[4], o1[4];
    #pragma unroll
    for (int q = 0; q < 4; ++q){
      float t0 = bias[q];
      t0 = fmaf(c0[0][q], kk[0][0][q], t0);
      t0 = fmaf(c1[0][q], kk[0][1][q], t0);
      t0 = fmaf(c2[0][q], kk[0][2][q], t0);
      t0 = fmaf(c0[1][q], kk[1][0][q], t0);
      t0 = fmaf(c1[1][q], kk[1][1][q], t0);
      t0 = fmaf(c2[1][q], kk[1][2][q], t0);
      t0 = fmaf(c0[2][q], kk[2][0][q], t0);
      t0 = fmaf(c1[2][q], kk[2][1][q], t0);
      t0 = fmaf(c2[2][q], kk[2][2][q], t0);
      o0[q] = t0;
      sum[q] += t0; sq[q] = fmaf(t0, t0, sq[q]);
      float t1 = bias[q];
      t1 = fmaf(c1[0][q], kk[0][0][q], t1);
      t1 = fmaf(c2[0][q], kk[0][1][q], t1);
      t1 = fmaf(c3[0][q], kk[0][2][q], t1);
      t1 = fmaf(c1[1][q], kk[1][0][q], t1);
      t1 = fmaf(c2[1][q], kk[1][1][q], t1);
      t1 = fmaf(c3[1][q], kk[1][2][q], t1);
      t1 = fmaf(c1[2][q], kk[2][0][q], t1);
      t1 = fmaf(c2[2][q], kk[2][1][q], t1);
      t1 = fmaf(c3[2][q], kk[2][2][q], t1);
      o1[q] = t1;
      sum[q] += t1; sq[q] = fmaf(t1, t1, sq[q]);
    }
    ushort4 ov0, ov1;
    ov0.x = f2bf(o0[0]); ov0.y = f2bf(o0[1]); ov0.z = f2bf(o0[2]); ov0.w = f2bf(o0[3]);
    ov1.x = f2bf(o1[0]); ov1.y = f2bf(o1[1]); ov1.z = f2bf(o1[2]); ov1.w = f2bf(o1[3]);
    *(ushort4*)&op[(size_t)x*NMED]     = ov0;
    *(ushort4*)&op[(size_t)(x+1)*NMED] = ov1;
    #pragma unroll
    for (int r = 0; r < 3; ++r)
      #pragma unroll
      for (int q = 0; q < 4; ++q){
        c0[r][q] = c2[r][q]; c1[r][q] = c3[r][q];
        c2[r][q] = n0[r][q]; c3[r][q] = n1[r][q];
      }
  }
  size_t pbase = ((size_t)((b*NH + y)*2 + seg))*NMED + c;
  float4 s4; s4.x=sum[0]; s4.y=sum[1]; s4.z=sum[2]; s4.w=sum[3];
  float4 q4; q4.x=sq[0];  q4.y=sq[1];  q4.z=sq[2];  q4.w=sq[3];
  *(float4*)&psum[pbase] = s4;
  *(float4*)&psq[pbase]  = q4;
}

// ---- BN reduction, two-stage parallel ----
__global__ __launch_bounds__(256) void k_bnpart(const float* __restrict__ psum, const float* __restrict__ psq,
    float* __restrict__ ps2, float* __restrict__ pq2){
  int idx = blockIdx.x*256 + threadIdx.x;
  int c  = idx % NMED;
  int jl = idx / NMED;
  float s = 0.f, q = 0.f;
  #pragma unroll
  for (int i = 0; i < (NB*NH*2)/32; ++i){
    int j = jl + i*32;
    s += psum[(size_t)j*NMED + c];
    q += psq [(size_t)j*NMED + c];
  }
  ps2[(size_t)jl*NMED + c] = s;
  pq2[(size_t)jl*NMED + c] = q;
}

__global__ __launch_bounds__(256) void k_bnfinal(const float* __restrict__ ps2, const float* __restrict__ pq2,
    const float* __restrict__ gamma, const float* __restrict__ beta,
    float* __restrict__ bnsc, float* __restrict__ bnsh){
  int c = blockIdx.x*256 + threadIdx.x;
  if (c >= NMED) return;
  float s = 0.f, q = 0.f;
  #pragma unroll 8
  for (int j = 0; j < 32; ++j){ s += ps2[(size_t)j*NMED + c]; q += pq2[(size_t)j*NMED + c]; }
  float mu  = s * (1.0f/(float)NPIX);
  float var = q * (1.0f/(float)NPIX) - mu*mu;
  float sc = gamma[c] * rsqrtf(var + 1e-5f);
  bnsc[c] = sc;
  bnsh[c] = beta[c] - mu*sc;
}

// ---------------- spectral stages (all MFMA) ----------------
// A1p packs (re,im) bf16 into one u32 per element: lo16=re, hi16=im.

// forward rDFT along W, 2 h-rows per block (E fragments reused across rows).
__global__ __launch_bounds__(256) void k_fftw_mfma(const u16* __restrict__ v,
    u32* __restrict__ A1p, const u16* __restrict__ gE){
  __shared__ u16 sE[64*64];        // 8 KB
  __shared__ u16 sV[2][128*64];    // 32 KB
  int t = threadIdx.x;
  int cs = blockIdx.x, hp = blockIdx.y, bz = blockIdx.z;

  ((int4*)sE)[t]       = ((const int4*)gE)[t];
  ((int4*)sE)[t + 256] = ((const int4*)gE)[t + 256];

  #pragma unroll
  for (int rr = 0; rr < 2; ++rr){
    int h = hp*2 + rr;
    int cg = (t & 15) * 8;
    int wq = (t >> 4) * 4;
    u16 buf[4][8];
    #pragma unroll
    for (int dw = 0; dw < 4; ++dw){
      int w = wq + dw;
      if (w < 56){
        *(int4*)&buf[dw][0] = *(const int4*)&v[((size_t)((bz*NH + h)*NW) + w)*NMED + (size_t)cs*128 + cg];
      } else {
        #pragma unroll
        for (int j = 0; j < 8; ++j) buf[dw][j] = 0;
      }
    }
    #pragma unroll
    for (int j = 0; j < 8; ++j){
      u16 tmp[4] = {buf[0][j], buf[1][j], buf[2][j], buf[3][j]};
      *(uint2*)&sV[rr][lix(cg + j, wq)] = *(uint2*)tmp;
    }
  }
  __syncthreads();

  int lane = t & 63, wid = t >> 6;
  int lr = lane & 15, kg = lane >> 4;
  int wn0 = wid * 32;
  f32x4 acc[2][4][2] = {};

  #pragma unroll
  for (int ks = 0; ks < 2; ++ks){
    int k0 = ks*32 + kg*8;
    s16x8 fE[4];
    #pragma unroll
    for (int mi = 0; mi < 4; ++mi) fE[mi] = *(const s16x8*)&sE[lix(mi*16 + lr, k0)];
    #pragma unroll
    for (int rr = 0; rr < 2; ++rr){
      #pragma unroll
      for (int ni = 0; ni < 2; ++ni){
        s16x8 bv = *(const s16x8*)&sV[rr][lix(wn0 + ni*16 + lr, k0)];
        #pragma unroll
        for (int mi = 0; mi < 4; ++mi)
          acc[rr][mi][ni] = __builtin_amdgcn_mfma_f32_16x16x32_bf16(fE[mi], bv, acc[rr][mi][ni], 0, 0, 0);
      }
    }
  }

  #pragma unroll
  for (int rr = 0; rr < 2; ++rr){
    int h = hp*2 + rr;
    size_t gb = ((size_t)bz*NWF*NH)*NMED + (size_t)h*NMED + (size_t)cs*128;
    #pragma unroll
    for (int mi = 0; mi < 4; ++mi){
      #pragma unroll
      for (int rp = 0; rp < 2; ++rp){
        int j0 = mi*16 + kg*4 + rp*2;
        int k2 = j0 >> 1;
        if (k2 < NWF){
          #pragma unroll
          for (int ni = 0; ni < 2; ++ni){
            int c = wn0 + ni*16 + lr;
            A1p[gb + (size_t)k2*NH*NMED + c] = packbf(acc[rr][mi][ni][rp*2], acc[rr][mi][ni][rp*2+1]);
          }
        }
      }
    }
  }
}

// Fused H-stage via MFMA, 64-channel tiles.
// P = E_f X ; P' = P .* W /3136 ; Q = E_i P'. In-place on A1p.
__global__ __launch_bounds__(256) void k_ffth_fused(u32* __restrict__ A1p,
    const u16* __restrict__ gC, const u16* __restrict__ gS,
    const float* __restrict__ rout, const float* __restrict__ cw){
  __shared__ u16 sC[64*64], sS[64*64];   // 8 KB each
  __shared__ u16 sXr[64*64], sXi[64*64]; // 8 KB each (X, then P')
  __shared__ float cwS[56*8];            // 1.8 KB -> total ~34 KB
  int t = threadIdx.x;
  int cs = blockIdx.x, k2 = blockIdx.y, bz = blockIdx.z;
  size_t gbase = ((size_t)(bz*NWF + k2)*NH)*NMED + (size_t)cs*64;

  ((int4*)sC)[t]       = ((const int4*)gC)[t];
  ((int4*)sC)[t + 256] = ((const int4*)gC)[t + 256];
  ((int4*)sS)[t]       = ((const int4*)gS)[t];
  ((int4*)sS)[t + 256] = ((const int4*)gS)[t + 256];

  for (int j = t; j < 56*8; j += 256){
    int k1 = j >> 3, f = j & 7;
    cwS[j] = cw[((size_t)(k1*NWF + k2))*8 + f];
  }
  {
    int c = t & 63;
    int hg = t >> 6;
    #pragma unroll
    for (int q = 0; q < 4; ++q){
      int h = hg*16 + q*4;
      u32 u0=0, u1=0, u2=0, u3=0;
      if (h < 56){
        const u32* gp = &A1p[gbase + (size_t)h*NMED + c];
        u0 = gp[0*NMED]; u1 = gp[1*NMED]; u2 = gp[2*NMED]; u3 = gp[3*NMED];
      }
      uint2 rr, ii;
      rr.x = (u0 & 0xffffu) | (u1 << 16);
      rr.y = (u2 & 0xffffu) | (u3 << 16);
      ii.x = (u0 >> 16) | (u1 & 0xffff0000u);
      ii.y = (u2 >> 16) | (u3 & 0xffff0000u);
      *(uint2*)&sXr[lix(c, h)] = rr;
      *(uint2*)&sXi[lix(c, h)] = ii;
    }
  }
  __syncthreads();

  int lane = t & 63, wid = t >> 6;
  int lr = lane & 15, kg = lane >> 4;
  int wn0 = wid * 16;                 // 4 waves x 16 channels = 64

  f32x4 aR[4], aI[4];
  #pragma unroll
  for (int mi = 0; mi < 4; ++mi){ aR[mi] = (f32x4){0,0,0,0}; aI[mi] = (f32x4){0,0,0,0}; }

  #pragma unroll
  for (int ks = 0; ks < 2; ++ks){
    int k0 = ks*32 + kg*8;
    s16x8 fC[4], fS[4];
    #pragma unroll
    for (int mi = 0; mi < 4; ++mi){
      fC[mi] = *(const s16x8*)&sC[lix(mi*16 + lr, k0)];
      fS[mi] = *(const s16x8*)&sS[lix(mi*16 + lr, k0)];
    }
    s16x8 xr = *(const s16x8*)&sXr[lix(wn0 + lr, k0)];
    s16x8 xi = *(const s16x8*)&sXi[lix(wn0 + lr, k0)];
    uint4 xu = *(uint4*)&xr;
    xu.x ^= 0x80008000u; xu.y ^= 0x80008000u; xu.z ^= 0x80008000u; xu.w ^= 0x80008000u;
    s16x8 xrn = *(s16x8*)&xu;
    #pragma unroll
    for (int mi = 0; mi < 4; ++mi){
      aR[mi] = __builtin_amdgcn_mfma_f32_16x16x32_bf16(fC[mi], xr,  aR[mi], 0,0,0);
      aR[mi] = __builtin_amdgcn_mfma_f32_16x16x32_bf16(fS[mi], xi,  aR[mi], 0,0,0);
      aI[mi] = __builtin_amdgcn_mfma_f32_16x16x32_bf16(fC[mi], xi,  aI[mi], 0,0,0);
      aI[mi] = __builtin_amdgcn_mfma_f32_16x16x32_bf16(fS[mi], xrn, aI[mi], 0,0,0);
    }
  }
  __syncthreads();

  const float inv = 1.0f/3136.0f;
  float rv0, rv1, rv2, rv3;
  {
    int cg = cs*64 + wn0 + lr;
    rv0 = rout[(bz*NFIL+0)*NMED + cg];
    rv1 = rout[(bz*NFIL+1)*NMED + cg];
    rv2 = rout[(bz*NFIL+2)*NMED + cg];
    rv3 = rout[(bz*NFIL+3)*NMED + cg];
  }
  #pragma unroll
  for (int mi = 0; mi < 4; ++mi){
    #pragma unroll
    for (int r = 0; r < 4; ++r){
      int k1 = mi*16 + kg*4 + r;
      float c0=0,c1=0,c2=0,c3=0,c4=0,c5=0,c6=0,c7=0;
      if (k1 < 56){
        const float* cp = cwS + k1*8;
        c0=cp[0]; c1=cp[1]; c2=cp[2]; c3=cp[3]; c4=cp[4]; c5=cp[5]; c6=cp[6]; c7=cp[7];
      }
      float wr = rv0*c0 + rv1*c2 + rv2*c4 + rv3*c6;
      float wi = rv0*c1 + rv1*c3 + rv2*c5 + rv3*c7;
      float pr = aR[mi][r], pi = aI[mi][r];
      float qr = (pr*wr - pi*wi) * inv;
      float qi = (pr*wi + pi*wr) * inv;
      int cl = wn0 + lr;
      sXr[lix(cl, k1)] = f2bf(qr);
      sXi[lix(cl, k1)] = f2bf(qi);
    }
  }
  __syncthreads();

  #pragma unroll
  for (int mi = 0; mi < 4; ++mi){ aR[mi] = (f32x4){0,0,0,0}; aI[mi] = (f32x4){0,0,0,0}; }
  #pragma unroll
  for (int ks = 0; ks < 2; ++ks){
    int k0 = ks*32 + kg*8;
    s16x8 fC[4], fS[4];
    #pragma unroll
    for (int mi = 0; mi < 4; ++mi){
      fC[mi] = *(const s16x8*)&sC[lix(mi*16 + lr, k0)];
      fS[mi] = *(const s16x8*)&sS[lix(mi*16 + lr, k0)];
    }
    s16x8 pr = *(const s16x8*)&sXr[lix(wn0 + lr, k0)];
    s16x8 pi = *(const s16x8*)&sXi[lix(wn0 + lr, k0)];
    uint4 pu = *(uint4*)&pi;
    pu.x ^= 0x80008000u; pu.y ^= 0x80008000u; pu.z ^= 0x80008000u; pu.w ^= 0x80008000u;
    s16x8 pin = *(s16x8*)&pu;
    #pragma unroll
    for (int mi = 0; mi < 4; ++mi){
      aR[mi] = __builtin_amdgcn_mfma_f32_16x16x32_bf16(fC[mi], pr,  aR[mi], 0,0,0);
      aR[mi] = __builtin_amdgcn_mfma_f32_16x16x32_bf16(fS[mi], pin, aR[mi], 0,0,0);
      aI[mi] = __builtin_amdgcn_mfma_f32_16x16x32_bf16(fC[mi], pi,  aI[mi], 0,0,0);
      aI[mi] = __builtin_amdgcn_mfma_f32_16x16x32_bf16(fS[mi], pr,  aI[mi], 0,0,0);
    }
  }

  #pragma unroll
  for (int mi = 0; mi < 4; ++mi){
    #pragma unroll
    for (int r = 0; r < 4; ++r){
      int n1 = mi*16 + kg*4 + r;
      if (n1 < 56){
        int cl = wn0 + lr;
        A1p[gbase + (size_t)n1*NMED + cl] = packbf(aR[mi][r], aI[mi][r]);
      }
    }
  }
}

// inverse along W via MFMA, 64-channel tiles, 2 n1-rows per block.
// Swapped operands: output fragment row=channel (4 consecutive/lane), col=w.
__global__ __launch_bounds__(256) void k_ifftw_mfma(const u32* __restrict__ Qp,
    const u16* __restrict__ gAB, const u16* __restrict__ locraw,
    const float* __restrict__ bnsc, const float* __restrict__ bnsh,
    const float* __restrict__ lsp, const float* __restrict__ lbp, u16* __restrict__ sbuf){
  __shared__ u16 sA[64*64];       // 8 KB
  __shared__ u16 sQ[2][64*64];    // 16 KB -> total 24 KB
  int t = threadIdx.x;
  int cs = blockIdx.x, np = blockIdx.y, bz = blockIdx.z;

  ((int4*)sA)[t]       = ((const int4*)gAB)[t];
  ((int4*)sA)[t + 256] = ((const int4*)gAB)[t + 256];

  {
    int c = t & 63;
    int g = t >> 6;
    #pragma unroll
    for (int rr = 0; rr < 2; ++rr){
      int n1 = np*2 + rr;
      size_t qb = (((size_t)bz*NWF)*NH + n1)*NMED + (size_t)cs*64 + c;
      u32 qv[8];
      #pragma unroll
      for (int i = 0; i < 8; ++i){
        int k2 = 4*i + g;
        qv[i] = (k2 < NWF) ? Qp[qb + (size_t)k2*NH*NMED] : 0u;
      }
      #pragma unroll
      for (int i = 0; i < 8; ++i){
        int k2 = 4*i + g;
        *(u32*)&sQ[rr][lix(c, 2*k2)] = qv[i];
      }
    }
  }
  __syncthreads();

  int lane = t & 63, wid = t >> 6;
  int lr = lane & 15, kg = lane >> 4;
  int wn0 = wid * 16;
  f32x4 acc[2][4] = {};

  #pragma unroll
  for (int ks = 0; ks < 2; ++ks){
    int k0 = ks*32 + kg*8;
    s16x8 fA[4];
    #pragma unroll
    for (int mi = 0; mi < 4; ++mi) fA[mi] = *(const s16x8*)&sA[lix(mi*16 + lr, k0)];
    #pragma unroll
    for (int rr = 0; rr < 2; ++rr){
      s16x8 fQ = *(const s16x8*)&sQ[rr][lix(wn0 + lr, k0)];
      #pragma unroll
      for (int mi = 0; mi < 4; ++mi)
        acc[rr][mi] = __builtin_amdgcn_mfma_f32_16x16x32_bf16(fQ, fA[mi], acc[rr][mi], 0, 0, 0);
    }
  }

  float ls = lsp[0], lb = lbp[0];
  #pragma unroll
  for (int rr = 0; rr < 2; ++rr){
    int n1 = np*2 + rr;
    size_t rowbase = ((size_t)(bz*NH + n1)*NW)*NMED + (size_t)cs*64;
    int c0 = wn0 + kg*4;
    float4 bs4 = *(const float4*)&bnsc[cs*64 + c0];
    float4 bh4 = *(const float4*)&bnsh[cs*64 + c0];
    #pragma unroll
    for (int mi = 0; mi < 4; ++mi){
      int w = mi*16 + lr;
      if (w < 56){
        size_t oi = rowbase + (size_t)w*NMED + c0;
        ushort4 l4 = *(const ushort4*)&locraw[oi];
        float lv, rl, loc;
        ushort4 ov;
        lv = fmaf(bf2f(l4.x), bs4.x, bh4.x); rl = fmaxf(lv, 0.f); loc = fmaf(ls*rl, rl, lb);
        ov.x = f2bf(acc[rr][mi][0] + loc);
        lv = fmaf(bf2f(l4.y), bs4.y, bh4.y); rl = fmaxf(lv, 0.f); loc = fmaf(ls*rl, rl, lb);
        ov.y = f2bf(acc[rr][mi][1] + loc);
        lv = fmaf(bf2f(l4.z), bs4.z, bh4.z); rl = fmaxf(lv, 0.f); loc = fmaf(ls*rl, rl, lb);
        ov.z = f2bf(acc[rr][mi][2] + loc);
        lv = fmaf(bf2f(l4.w), bs4.w, bh4.w); rl = fmaxf(lv, 0.f); loc = fmaf(ls*rl, rl, lb);
        ov.w = f2bf(acc[rr][mi][3] + loc);
        *(ushort4*)&sbuf[oi] = ov;
      }
    }
  }
}

// ---------------- host launch ----------------

extern "C" void kernel_launch(void* const* d_in, const int* in_sizes, int n_in,
                              void* d_out, int out_size, void* d_ws, size_t ws_size,
                              hipStream_t stream){
  const float* x       = (const float*)d_in[0];
  const float* w_pw1   = (const float*)d_in[1];
  const float* w_pw2   = (const float*)d_in[2];
  const float* a1s     = (const float*)d_in[3];
  const float* a1b     = (const float*)d_in[4];
  const float* w_r1    = (const float*)d_in[5];
  const float* r_s     = (const float*)d_in[6];
  const float* r_b     = (const float*)d_in[7];
  const float* w_r2    = (const float*)d_in[8];
  const float* dwk     = (const float*)d_in[9];
  const float* dwb     = (const float*)d_in[10];
  const float* bng     = (const float*)d_in[11];
  const float* bnb     = (const float*)d_in[12];
  const float* l_s     = (const float*)d_in[13];
  const float* l_b     = (const float*)d_in[14];
  const float* cw      = (const float*)d_in[15];
  float* out = (float*)d_out;

  char* ws = (char*)d_ws;
  size_t off = 0;
  auto al = [&](size_t n)->size_t{ off = (off + 255) & ~(size_t)255; size_t r = off; off += n; return r; };
  size_t o_gE  = al((size_t)64*64*2);
  size_t o_gC  = al((size_t)64*64*2);
  size_t o_gS  = al((size_t)64*64*2);
  size_t o_gAB = al((size_t)64*64*2);
  size_t o_wT1 = al((size_t)NMED*NDIM*2);
  size_t o_wT2 = al((size_t)NDIM*NMED*2);
  size_t o_xbf = al((size_t)NPIX*NDIM*2);
  size_t o_gp  = al((size_t)NB*NH*NDIM*4);
  size_t o_g   = al((size_t)NB*NDIM*4);
  size_t o_h   = al((size_t)NB*NRH*4);
  size_t o_rt  = al((size_t)NB*NFIL*NMED*4);
  size_t o_ps  = al((size_t)NB*NH*2*NMED*4);
  size_t o_pq  = al((size_t)NB*NH*2*NMED*4);
  size_t o_p2s = al((size_t)32*NMED*4);
  size_t o_p2q = al((size_t)32*NMED*4);
  size_t o_bs  = al((size_t)NMED*4);
  size_t o_bh  = al((size_t)NMED*4);
  size_t o_v   = al((size_t)NPIX*NMED*2);

  const size_t a1_per_batch = (size_t)NWF*NH*NMED*4;
  int CH = 16;
  size_t o_A1 = 0, need = 0;
  for (;;){
    size_t o2 = off;
    auto al2 = [&](size_t n)->size_t{ o2 = (o2 + 255) & ~(size_t)255; size_t r = o2; o2 += n; return r; };
    o_A1 = al2((size_t)CH*a1_per_batch);
    need = o2;
    if (need <= ws_size || CH == 1) break;
    CH >>= 1;
  }
  if (need > ws_size) return;

  u16* gE  = (u16*)(ws + o_gE);
  u16* gC  = (u16*)(ws + o_gC);
  u16* gS  = (u16*)(ws + o_gS);
  u16* gAB = (u16*)(ws + o_gAB);
  u16* wT1 = (u16*)(ws + o_wT1);
  u16* wT2 = (u16*)(ws + o_wT2);
  u16* xbf = (u16*)(ws + o_xbf);
  float* gp = (float*)(ws + o_gp);
  float* g  = (float*)(ws + o_g);
  float* hb = (float*)(ws + o_h);
  float* rt = (float*)(ws + o_rt);
  float* ps = (float*)(ws + o_ps);
  float* pq = (float*)(ws + o_pq);
  float* p2s = (float*)(ws + o_p2s);
  float* p2q = (float*)(ws + o_p2q);
  float* bs = (float*)(ws + o_bs);
  float* bh = (float*)(ws + o_bh);
  u16* v   = (u16*)(ws + o_v);
  u32* A1p = (u32*)(ws + o_A1);
  u16* lraw = (u16*)d_out;

  k_prep<<<4, 256, 0, stream>>>(gE, gC, gS, gAB);
  k_wt<<<(NDIM*NMED+255)/256, 256, 0, stream>>>(w_pw1, wT1, NDIM, NMED);
  k_wt<<<(NMED*NDIM+255)/256, 256, 0, stream>>>(w_pw2, wT2, NMED, NDIM);

  // gpart streams x once: computes GAP partials AND writes bf16 copy of x
  k_gpart<<<dim3(NH, NB), 384, 0, stream>>>(x, gp, xbf);
  k_gfinal<<<NB, 384, 0, stream>>>(gp, g);
  k_rmlp1<<<NB, 128, 0, stream>>>(g, w_r1, r_s, r_b, hb);
  k_rmlp2<<<dim3(NMED/256, NB), 256, 0, stream>>>(hb, w_r2, rt);

  // v = StarReLU(x @ w_pw1): global_load_lds GEMM on bf16 A
  gemm_glds<0><<<dim3(NMED/128, NPIX/128), 256, 0, stream>>>(xbf, wT1, nullptr, v,
      NPIX, NMED, NDIM, a1s, a1b);

  k_dwconv<<<dim3(2, NH, NB), 192, 0, stream>>>(v, dwk, dwb, lraw, ps, pq);
  k_bnpart<<<(32*NMED)/256, 256, 0, stream>>>(ps, pq, p2s, p2q);
  k_bnfinal<<<3, 256, 0, stream>>>(p2s, p2q, bng, bnb, bs, bh);

  for (int b0 = 0; b0 < NB; b0 += CH){
    size_t pixoff = (size_t)b0*NH*NW*NMED;
    k_fftw_mfma <<<dim3(NMED/128, NH/2, CH), 256, 0, stream>>>(v + pixoff, A1p, gE);
    k_ffth_fused<<<dim3(NMED/64,  NWF,  CH), 256, 0, stream>>>(A1p, gC, gS,
                                                               rt + (size_t)b0*NFIL*NMED, cw);
    k_ifftw_mfma<<<dim3(NMED/64,  NH/2, CH), 256, 0, stream>>>(A1p, gAB, lraw + pixoff, bs, bh,
                                                               l_s, l_b, v + pixoff);
  }

  // out = (y + loc) @ w_pw2: A (=v) already bf16 -> global_load_lds GEMM
  gemm_glds<1><<<dim3(NDIM/128, NPIX/128), 256, 0, stream>>>(v, wT2, out, nullptr,
      NPIX, NDIM, NMED, nullptr, nullptr);
}